// Round 8
// baseline (3924.948 us; speedup 1.0000x reference)
//
#include <hip/hip_runtime.h>
#include <hip/hip_bf16.h>
#include <cstdint>
#include <cstddef>

// ---------------- ws layout (float offsets) ----------------
constexpr size_t OFF_MEM    = 0;          // 65536   (unused; layout kept)
constexpr size_t OFF_XM     = 65536;      // 16384   xm[d][t] transposed (d*64+t)
constexpr size_t OFF_MU     = 82176;      // 16384   mu[t][d]
constexpr size_t OFF_SABS   = 98560;      // 64*4    per-step surprise sums (3 frames)
constexpr size_t OFF_BAR    = 98816;      // 1       grid-barrier epoch counter (zeroed by k0)
constexpr size_t ZERO_END   = 98880;
constexpr size_t OFF_WBAR   = 98880;      // 65536   Wbar = mean_n W  [d][e]
constexpr size_t OFF_MEANS  = 164416;     // (unused; layout kept)
constexpr size_t OFF_VARS   = 361024;     // (unused; layout kept)
constexpr size_t OFF_DT     = 557632;     // 64*256  tridiagonal diag
constexpr size_t OFF_ET     = 574016;     // 64*256  tridiagonal offdiag
constexpr size_t OFF_RHO    = 590400;     // 64*65536: meas[n][t][e] first, then rho[t] (aliased)
constexpr size_t OFF_MN16   = 4784704;    // bf16 mn [64][256][256] = 2097152 floats
constexpr size_t OFF_E16    = 6881856;    // bf16 E  [32000][256]  = 4096000 floats
constexpr size_t WS_FLOATS  = 10977856;   // ~41.9 MiB

#define SEQ_ 64
#define VOCAB_ 32000

typedef __attribute__((ext_vector_type(8))) short bf16x8;
typedef __attribute__((ext_vector_type(4))) float f32x4;

// ---------------- reduction helpers ----------------
__device__ __forceinline__ float wave_sum(float v){
  v += __shfl_xor(v, 32); v += __shfl_xor(v, 16); v += __shfl_xor(v, 8);
  v += __shfl_xor(v, 4);  v += __shfl_xor(v, 2);  v += __shfl_xor(v, 1);
  return v;
}
__device__ __forceinline__ float block_sum(float v, float* red){
  int tid = threadIdx.x;
  v = wave_sum(v);
  if ((tid & 63) == 0) red[tid >> 6] = v;
  __syncthreads();
  float r = red[0] + red[1] + red[2] + red[3];
  __syncthreads();
  return r;
}
__device__ __forceinline__ float block_min(float v, float* red){
  int tid = threadIdx.x;
  v = fminf(v, __shfl_xor(v, 32)); v = fminf(v, __shfl_xor(v, 16));
  v = fminf(v, __shfl_xor(v, 8));  v = fminf(v, __shfl_xor(v, 4));
  v = fminf(v, __shfl_xor(v, 2));  v = fminf(v, __shfl_xor(v, 1));
  if ((tid & 63) == 0) red[tid >> 6] = v;
  __syncthreads();
  float r = fminf(fminf(red[0], red[1]), fminf(red[2], red[3]));
  __syncthreads();
  return r;
}
__device__ __forceinline__ float block_max(float v, float* red){
  int tid = threadIdx.x;
  v = fmaxf(v, __shfl_xor(v, 32)); v = fmaxf(v, __shfl_xor(v, 16));
  v = fmaxf(v, __shfl_xor(v, 8));  v = fmaxf(v, __shfl_xor(v, 4));
  v = fmaxf(v, __shfl_xor(v, 2));  v = fmaxf(v, __shfl_xor(v, 1));
  if ((tid & 63) == 0) red[tid >> 6] = v;
  __syncthreads();
  float r = fmaxf(fmaxf(red[0], red[1]), fmaxf(red[2], red[3]));
  __syncthreads();
  return r;
}

// ---------------- K0: zero state + E -> bf16 ----------------
__global__ __launch_bounds__(256) void k0_init(const float* __restrict__ E, float* __restrict__ ws){
  size_t i = (size_t)blockIdx.x * 256 + threadIdx.x;   // exactly 8,192,000 threads
  if (i < ZERO_END) ws[i] = 0.f;
  __hip_bfloat16* e16 = (__hip_bfloat16*)(ws + OFF_E16);
  e16[i] = __float2bfloat16(E[i]);
}

// ---------------- K_wbar: Wbar[d][e] = mean_n W[n][d][e] ----------------
__global__ __launch_bounds__(256) void k_wbar(const float* __restrict__ W, float* __restrict__ ws){
  size_t i = (size_t)blockIdx.x * 256 + threadIdx.x;   // 65536 threads
  float s = 0.f;
  #pragma unroll 4
  for (int n = 0; n < 256; ++n)
    s += W[(size_t)n * 65536 + i];
  ws[OFF_WBAR + i] = s * (1.0f / 256.0f);
}

// ---------------- K_xm: sequential scalar recurrence (1 block, 1024 threads) ----------------
__global__ __launch_bounds__(1024) void k_xm(const int* __restrict__ tokens,
    const float* __restrict__ E, const float* __restrict__ mdbp,
    const float* __restrict__ nsp, float* __restrict__ ws){
  __shared__ float xm_s[256];
  __shared__ __align__(16) float part[4][256];
  __shared__ float redA[16], redB[16], redC[16];
  const int tid = threadIdx.x;
  const int e = tid & 255, q = tid >> 8;
  const int lane = tid & 63, w = tid >> 6;
  const float sens = fabsf(nsp[0]);
  const float mdb  = mdbp[0];
  const float* Wb = ws + OFF_WBAR;
  float mm = 0.f;                                    // valid on tid<256; 0 elsewhere

  for (int t = 0; t < SEQ_; ++t){
    int tok = tokens[t];
    float xv = (tid < 256) ? E[(size_t)tok * 256 + e] : 0.f;
    float a = wave_sum(xv * mm);
    float b = wave_sum(xv * xv);
    float c = wave_sum(mm * mm);
    if (lane == 0){ redA[w] = a; redB[w] = b; redC[w] = c; }
    __syncthreads();                                 // S1: partials ready
    float sdot = (redA[0] + redA[1]) + (redA[2] + redA[3]);
    float sx2  = (redB[0] + redB[1]) + (redB[2] + redB[3]);
    float sm2  = (redC[0] + redC[1]) + (redC[2] + redC[3]);
    float mem_norm = sqrtf(sm2) + 1e-10f;
    float x_norm   = sqrtf(sx2) + 1e-10f;
    float novelty = (mem_norm > 1e-8f) ? (1.0f - sdot / (x_norm * mem_norm)) : 1.0f;
    float z = mdb - sens * novelty;
    float decay = 1.0f / (1.0f + expf(-z));
    if (tid < 256){
      float xmv = xv + decay * mm;
      xm_s[e] = xmv;
      ws[OFF_XM + (size_t)e * 64 + t] = xmv;         // transposed for k_measall
    }
    __syncthreads();                                 // S2: xm_s ready

    const float* Wq = Wb + (size_t)(q * 64) * 256 + e;
    float p = 0.f;
    #pragma unroll 16
    for (int dd = 0; dd < 64; ++dd)
      p = fmaf(xm_s[q * 64 + dd], Wq[(size_t)dd * 256], p);
    part[q][e] = p;
    __syncthreads();                                 // S3: partials ready
    if (tid < 256){
      float acc = (part[0][e] + part[1][e]) + (part[2][e] + part[3][e]);
      ws[OFF_MU + (size_t)t * 256 + e] = acc;
      mm = decay * mm + (1.0f - decay) * acc;
    }
    __syncthreads();                                 // S4: reuse guard
  }
}

// ---------------- K_measall: meas[n][t][e] = sum_d xm[t][d] W[n][d][e] ----------------
__global__ __launch_bounds__(256) void k_measall(const float* __restrict__ W, float* __restrict__ ws){
  __shared__ __align__(16) float xm_s[16384];        // [d][t] (d*64+t)
  const int tid = threadIdx.x, n = blockIdx.x;
  for (int i = tid; i < 16384; i += 256) xm_s[i] = ws[OFF_XM + i];
  __syncthreads();

  float acc[64];
  #pragma unroll
  for (int t = 0; t < 64; ++t) acc[t] = 0.f;

  const float* Wn = W + (size_t)n * 65536 + tid;
  for (int d = 0; d < 256; ++d){
    float wv = Wn[(size_t)d * 256];
    const float* xr = &xm_s[d * 64];
    #pragma unroll
    for (int q = 0; q < 16; ++q){
      float4 x4 = *(const float4*)&xr[q * 4];
      acc[q * 4 + 0] = fmaf(x4.x, wv, acc[q * 4 + 0]);
      acc[q * 4 + 1] = fmaf(x4.y, wv, acc[q * 4 + 1]);
      acc[q * 4 + 2] = fmaf(x4.z, wv, acc[q * 4 + 2]);
      acc[q * 4 + 3] = fmaf(x4.w, wv, acc[q * 4 + 3]);
    }
  }
  #pragma unroll
  for (int t = 0; t < 64; ++t)
    ws[OFF_RHO + (size_t)n * 16384 + (size_t)t * 256 + tid] = acc[t];
}

// ---------------- K_stats: sequential know/means/vars recurrence ----------------
__global__ __launch_bounds__(1024, 1) void k_stats(float* __restrict__ ws){
  __shared__ float redA[16], redB[16], redC[16];
  const int tid = threadIdx.x;
  const int e = tid & 255, q = tid >> 8;
  const int lane = tid & 63, w = tid >> 6;
  const int n = blockIdx.x * 4 + q;
  unsigned* bar = (unsigned*)(ws + OFF_BAR);
  __hip_bfloat16* mn16 = (__hip_bfloat16*)(ws + OFF_MN16);
  const size_t ne = (size_t)n * 256 + e;
  const float TH = 1.5f * 65536.0f;
  const float c5 = 0.59049f;                         // 0.9^5

  float mean0 = 0.f, mean1 = 0.f, mean2 = 0.f;
  float var0 = 0.f, var1 = 0.f, var2 = 0.f;

  for (int t = 0; t < SEQ_; ++t){
    float me = ws[OFF_RHO + (size_t)n * 16384 + (size_t)t * 256 + e];
    bool know = false;
    if (t > 0){
      float v0 = fabsf(me - mean0) / sqrtf(var0 + 1e-8f);
      float v1 = fabsf(me - mean1) / sqrtf(var1 + 1e-8f);
      float v2 = fabsf(me - mean2) / sqrtf(var2 + 1e-8f);
      float a = wave_sum(v0), b = wave_sum(v1), c = wave_sum(v2);
      if (lane == 0){ redA[w] = a; redB[w] = b; redC[w] = c; }
      __syncthreads();                               // S1: partials ready
      if (tid == 0){
        float sA = 0.f, sB = 0.f, sC = 0.f;
        #pragma unroll
        for (int i = 0; i < 16; ++i){ sA += redA[i]; sB += redB[i]; sC += redC[i]; }
        atomicAdd(&ws[OFF_SABS + (size_t)t * 4 + 0], sA);
        atomicAdd(&ws[OFF_SABS + (size_t)t * 4 + 1], sB);
        atomicAdd(&ws[OFF_SABS + (size_t)t * 4 + 2], sC);
        __hip_atomic_fetch_add(bar, 1u, __ATOMIC_ACQ_REL, __HIP_MEMORY_SCOPE_AGENT);
        unsigned tgt = 64u * (unsigned)t;
        while (__hip_atomic_load(bar, __ATOMIC_ACQUIRE, __HIP_MEMORY_SCOPE_AGENT) < tgt)
          __builtin_amdgcn_s_sleep(2);
      }
      __syncthreads();                               // S2: sabs complete everywhere
      float s0 = __hip_atomic_load(&ws[OFF_SABS + (size_t)t * 4 + 0], __ATOMIC_RELAXED, __HIP_MEMORY_SCOPE_AGENT);
      float s1 = __hip_atomic_load(&ws[OFF_SABS + (size_t)t * 4 + 1], __ATOMIC_RELAXED, __HIP_MEMORY_SCOPE_AGENT);
      float s2 = __hip_atomic_load(&ws[OFF_SABS + (size_t)t * 4 + 2], __ATOMIC_RELAXED, __HIP_MEMORY_SCOPE_AGENT);
      know = (s0 < TH) || (s1 < TH) || (s2 < TH);
    }
    float mu = ws[OFF_MU + (size_t)t * 256 + e];
    float eq = c5 * me + (1.0f - c5) * mu;
    float eff = know ? me : eq;

    if (t == 0){
      mean0 = eff; mean1 = eff; mean2 = eff;
      var0 = 0.1f; var1 = 0.1f; var2 = 0.1f;
    } else {
      float um, uv;
      um = 0.3f * mean0 + 0.7f * eff;
      uv = 0.3f * var0 + 0.7f * (eff - mean0) * (eff - um);
      mean0 = um; var0 = fmaxf(uv, 1e-8f);
      um = 0.7f * mean1 + 0.3f * eff;
      uv = 0.7f * var1 + 0.3f * (eff - mean1) * (eff - um);
      mean1 = um; var1 = fmaxf(uv, 1e-8f);
      um = 0.9f * mean2 + 0.1f * eff;
      uv = 0.9f * var2 + 0.1f * (eff - mean2) * (eff - um);
      mean2 = um; var2 = fmaxf(uv, 1e-8f);
    }

    float nv = wave_sum(eff * eff);
    if (lane == 0) redA[w] = nv;
    __syncthreads();                                 // S3: quarter partials
    float nr2 = (redA[4 * q + 0] + redA[4 * q + 1]) + (redA[4 * q + 2] + redA[4 * q + 3]);
    float rn = sqrtf(nr2) + 1e-10f;
    mn16[(size_t)t * 65536 + ne] = __float2bfloat16(eff / rn);
    __syncthreads();                                 // S4: red reuse guard
  }
}

// ---------------- K_rho: rho[t] = mn^T mn / NB (fp32 accum from bf16) ----------------
__global__ __launch_bounds__(256) void k_rho(float* __restrict__ ws){
  const int t = blockIdx.x, rb = blockIdx.y, tid = threadIdx.x;
  __shared__ __align__(16) float tile[32][256];
  const __hip_bfloat16* mn16 = (const __hip_bfloat16*)(ws + OFF_MN16);
  float acc[32];
  #pragma unroll
  for (int i = 0; i < 32; ++i) acc[i] = 0.f;
  for (int c = 0; c < 8; ++c){
    __syncthreads();
    for (int j = tid; j < 8192; j += 256){
      int row = j >> 8, col = j & 255;
      tile[row][col] = __bfloat162float(mn16[(size_t)t * 65536 + (size_t)(c * 32 + row) * 256 + col]);
    }
    __syncthreads();
    for (int nl = 0; nl < 32; ++nl){
      float ev = tile[nl][tid];
      #pragma unroll
      for (int q = 0; q < 8; ++q){
        float4 dv = *(const float4*)&tile[nl][rb * 32 + q * 4];
        acc[q * 4 + 0] = fmaf(dv.x, ev, acc[q * 4 + 0]);
        acc[q * 4 + 1] = fmaf(dv.y, ev, acc[q * 4 + 1]);
        acc[q * 4 + 2] = fmaf(dv.z, ev, acc[q * 4 + 2]);
        acc[q * 4 + 3] = fmaf(dv.w, ev, acc[q * 4 + 3]);
      }
    }
  }
  #pragma unroll
  for (int i = 0; i < 32; ++i)
    ws[OFF_RHO + (size_t)t * 65536 + (size_t)(rb * 32 + i) * 256 + tid] = acc[i] * (1.0f / 256.0f);
}

// ---------------- K_tri: Householder tridiagonalization, 1024 threads, Mreg[64] ----------------
// Proven 7-barrier arithmetic (round-0/5/6, byte-identical math), re-dimensioned:
// thread (c = tid&255, h = tid>>8 in [0,4)) holds rows [64h,64h+64) of column c
// in 64 TRUE VGPRs (1024-thread block caps VGPR at 128/wave -> no AGPR shuttle).
// 16 waves = 4/SIMD doubles latency hiding; every serial phase halves per-thread.
__global__ __launch_bounds__(1024, 1) void k_tri(float* __restrict__ ws){
  __shared__ __align__(16) float ca[256];   // raw column k
  __shared__ __align__(16) float ua[256];   // u
  __shared__ __align__(16) float wa[256];   // w
  __shared__ __align__(16) float ph[1024];  // per-(c,h) partial dots
  __shared__ float redA[16], redB[16];
  const int t = blockIdx.x, tid = threadIdx.x;
  const int c = tid & 255, h = tid >> 8;
  const float* rho = ws + OFF_RHO + (size_t)t * 65536;
  float* dT = ws + OFF_DT + (size_t)t * 256;
  float* eT = ws + OFF_ET + (size_t)t * 256;

  // load my quarter-column into registers (coalesced: lanes = consecutive c)
  float Mreg[64];
  {
    const float* Mc = rho + (size_t)(h * 64) * 256 + c;
    #pragma unroll
    for (int rr = 0; rr < 64; ++rr)
      Mreg[rr] = Mc[(size_t)rr * 256];
  }
  const int rowbase = h * 64;

  for (int k = 0; k < 254; ++k){
    __syncthreads();                                  // S1: prev update done
    if (c == k){                                      // dump my column (4 threads)
      #pragma unroll
      for (int rr = 0; rr < 64; ++rr) ca[rowbase + rr] = Mreg[rr];
    }
    __syncthreads();                                  // S2: ca visible
    float uval = 0.f;
    if (tid < 256){
      float raw = ca[tid];
      uval = (tid > k) ? raw : 0.f;
      ua[tid] = uval;
      if (tid == 0) dT[k] = ca[k];
    }
    float pa = wave_sum(uval * uval);
    if ((tid & 63) == 0) redA[tid >> 6] = pa;
    __syncthreads();                                  // S3: ua + redA
    float sigma2;
    {
      float4 rA0 = *(const float4*)&redA[0];
      float4 rA1 = *(const float4*)&redA[4];
      float4 rA2 = *(const float4*)&redA[8];
      float4 rA3 = *(const float4*)&redA[12];
      sigma2 = (((rA0.x + rA0.y) + (rA0.z + rA0.w)) + ((rA1.x + rA1.y) + (rA1.z + rA1.w)))
             + (((rA2.x + rA2.y) + (rA2.z + rA2.w)) + ((rA3.x + rA3.y) + (rA3.z + rA3.w)));
    }
    float v0 = ca[k + 1];
    if (sigma2 < 1e-30f){                             // uniform branch
      if (tid == 0) eT[k] = v0;
      continue;                                       // H = I
    }
    float sig = sqrtf(sigma2);
    float alpha = (v0 >= 0.f) ? -sig : sig;
    float u0 = v0 - alpha;
    float beta = 2.0f / (sigma2 - v0 * v0 + u0 * u0);
    if (tid == 0) eT[k] = alpha;
    if (tid == k + 1) ua[tid] = u0;
    __syncthreads();                                  // S4: u final

    // dot: ph = sum over my rows of M[r][c] * u_r (u reads are wave-uniform b128)
    {
      float a0 = 0.f, a1 = 0.f, a2 = 0.f, a3 = 0.f;
      #pragma unroll
      for (int rr = 0; rr < 64; rr += 4){
        float4 u4 = *(const float4*)&ua[rowbase + rr];
        a0 = fmaf(Mreg[rr + 0], u4.x, a0);
        a1 = fmaf(Mreg[rr + 1], u4.y, a1);
        a2 = fmaf(Mreg[rr + 2], u4.z, a2);
        a3 = fmaf(Mreg[rr + 3], u4.w, a3);
      }
      ph[tid] = (a0 + a1) + (a2 + a3);
    }
    __syncthreads();                                  // S5: ph
    float p = (ph[c] + ph[c + 256]) + (ph[c + 512] + ph[c + 768]);  // (A u)_c
    float up = (tid < 256) ? ua[tid] * p : 0.f;
    float pb = wave_sum(up);
    if ((tid & 63) == 0) redB[tid >> 6] = pb;
    __syncthreads();                                  // S6: redB
    float s;
    {
      float4 rB0 = *(const float4*)&redB[0];
      float4 rB1 = *(const float4*)&redB[4];
      float4 rB2 = *(const float4*)&redB[8];
      float4 rB3 = *(const float4*)&redB[12];
      s = (((rB0.x + rB0.y) + (rB0.z + rB0.w)) + ((rB1.x + rB1.y) + (rB1.z + rB1.w)))
        + (((rB2.x + rB2.y) + (rB2.z + rB2.w)) + ((rB3.x + rB3.y) + (rB3.z + rB3.w)));
    }
    if (tid < 256) wa[tid] = (tid > k) ? (beta * p - 0.5f * beta * beta * s * ua[tid]) : 0.f;
    __syncthreads();                                  // S7: wa
    // update: M[r][c] -= u_r w_c + w_r u_c   (all in registers)
    {
      float ucv = ua[c], wcv = wa[c];
      #pragma unroll
      for (int rr = 0; rr < 64; rr += 4){
        float4 u4 = *(const float4*)&ua[rowbase + rr];
        float4 w4 = *(const float4*)&wa[rowbase + rr];
        Mreg[rr + 0] = fmaf(-w4.x, ucv, fmaf(-u4.x, wcv, Mreg[rr + 0]));
        Mreg[rr + 1] = fmaf(-w4.y, ucv, fmaf(-u4.y, wcv, Mreg[rr + 1]));
        Mreg[rr + 2] = fmaf(-w4.z, ucv, fmaf(-u4.z, wcv, Mreg[rr + 2]));
        Mreg[rr + 3] = fmaf(-w4.w, ucv, fmaf(-u4.w, wcv, Mreg[rr + 3]));
      }
    }
  }

  // tail: dT[254], dT[255], eT[254]
  __syncthreads();
  if (c == 254){
    #pragma unroll
    for (int rr = 0; rr < 64; ++rr) ca[rowbase + rr] = Mreg[rr];
  }
  __syncthreads();
  if (tid == 0){ dT[254] = ca[254]; eT[254] = ca[255]; }
  __syncthreads();
  if (c == 255){
    #pragma unroll
    for (int rr = 0; rr < 64; ++rr) ca[rowbase + rr] = Mreg[rr];
  }
  __syncthreads();
  if (tid == 0){ dT[255] = ca[255]; eT[255] = 0.f; }
}

// ---------------- K_bisect: Sturm bisection, one eigenvalue per thread ----------------
__global__ __launch_bounds__(256) void k_bisect(const float* __restrict__ ws, float* __restrict__ out){
  __shared__ float d_s[256];
  __shared__ float e2_s[256];
  __shared__ float ea_s[256];
  __shared__ float red[4];
  const int t = blockIdx.x, tid = threadIdx.x;
  d_s[tid] = ws[OFF_DT + (size_t)t * 256 + tid];
  float evv = (tid < 255) ? ws[OFF_ET + (size_t)t * 256 + tid] : 0.f;
  e2_s[tid] = evv * evv;
  ea_s[tid] = fabsf(evv);
  __syncthreads();
  float rad = ea_s[tid] + ((tid > 0) ? ea_s[tid - 1] : 0.f);
  float glo = block_min(d_s[tid] - rad, red);
  float ghi = block_max(d_s[tid] + rad, red);

  float l = glo, h = ghi;
  for (int it = 0; it < 40; ++it){
    float mid = 0.5f * (l + h);
    float q = d_s[0] - mid;
    int cnt = (q < 0.f) ? 1 : 0;
    #pragma unroll 8
    for (int i = 1; i < 256; ++i){
      float qr = __builtin_amdgcn_rcpf(q);
      q = (d_s[i] - mid) - e2_s[i - 1] * qr;
      q = (fabsf(q) < 1e-25f) ? -1e-25f : q;
      cnt += (q < 0.f) ? 1 : 0;
    }
    if (cnt <= tid) l = mid; else h = mid;
  }
  float lam = fmaxf(0.5f * (l + h), 1e-12f);
  float ssum = block_sum(lam, red);
  out[(size_t)SEQ_ * VOCAB_ + (size_t)t * 256 + tid] = lam / ssum;
}

// ---------------- K_gemm: logits[t,v] = (1/NB) * sum_n (E[v]·mn_t[n])^2 ----------------
__global__ __launch_bounds__(512) void k_gemm(const float* __restrict__ ws, float* __restrict__ out){
  __shared__ __align__(16) short A_lds[128 * 64];   // E tile [128 v][8 chunks of 8]
  __shared__ __align__(16) short B_lds[256 * 64];   // mn tile [256 n][8 chunks of 8]
  __shared__ float pl[8][64];
  const int tid = threadIdx.x;
  const int bx = blockIdx.x, t = blockIdx.y;
  const int lane = tid & 63, w = tid >> 6;
  const int wr = w >> 2, wc = w & 3;
  const int vbase = bx * 128;
  const short* E16 = (const short*)(ws + OFF_E16);
  const short* MN  = (const short*)(ws + OFF_MN16) + (size_t)t * 65536;

  f32x4 acc[4][4];
  #pragma unroll
  for (int i = 0; i < 4; ++i)
    #pragma unroll
    for (int j = 0; j < 4; ++j){ f32x4 z = {0.f, 0.f, 0.f, 0.f}; acc[i][j] = z; }

  const int g = lane >> 4, r16 = lane & 15;
  const int sx = r16 & 7;                            // read-side XOR key
  for (int it = 0; it < 4; ++it){
    const int k0 = it * 64;
    __syncthreads();
    #pragma unroll
    for (int pa = 0; pa < 2; ++pa){
      int ch = pa * 512 + tid;
      int row = ch >> 3, c8 = ch & 7;
      int sc8 = c8 ^ (row & 7);                      // pre-swizzled source chunk
      uint4 v = *(const uint4*)(E16 + (size_t)(vbase + row) * 256 + k0 + sc8 * 8);
      *(uint4*)&A_lds[ch * 8] = v;                   // linear dest (conflict-free)
    }
    #pragma unroll
    for (int pb = 0; pb < 4; ++pb){
      int ch = pb * 512 + tid;
      int row = ch >> 3, c8 = ch & 7;
      int sc8 = c8 ^ (row & 7);
      uint4 v = *(const uint4*)(MN + (size_t)row * 256 + k0 + sc8 * 8);
      *(uint4*)&B_lds[ch * 8] = v;
    }
    __syncthreads();
    #pragma unroll
    for (int kk = 0; kk < 64; kk += 32){
      const int j0 = (kk >> 3) + g;                  // logical chunk index
      bf16x8 af[4], bf[4];
      #pragma unroll
      for (int fm = 0; fm < 4; ++fm)
        af[fm] = *(const bf16x8*)&A_lds[(wr * 64 + fm * 16 + r16) * 64 + (j0 ^ sx) * 8];
      #pragma unroll
      for (int fn = 0; fn < 4; ++fn)
        bf[fn] = *(const bf16x8*)&B_lds[(wc * 64 + fn * 16 + r16) * 64 + (j0 ^ sx) * 8];
      #pragma unroll
      for (int fm = 0; fm < 4; ++fm)
        #pragma unroll
        for (int fn = 0; fn < 4; ++fn)
          acc[fm][fn] = __builtin_amdgcn_mfma_f32_16x16x32_bf16(af[fm], bf[fn], acc[fm][fn], 0, 0, 0);
    }
  }

  // epilogue: square + reduce over n
  float ps[4][4];
  #pragma unroll
  for (int fm = 0; fm < 4; ++fm)
    #pragma unroll
    for (int i = 0; i < 4; ++i){
      float sv = 0.f;
      #pragma unroll
      for (int fn = 0; fn < 4; ++fn){ float v = acc[fm][fn][i]; sv += v * v; }
      sv += __shfl_xor(sv, 1); sv += __shfl_xor(sv, 2);
      sv += __shfl_xor(sv, 4); sv += __shfl_xor(sv, 8);
      ps[fm][i] = sv;
    }
  __syncthreads();
  if (r16 == 0){
    #pragma unroll
    for (int fm = 0; fm < 4; ++fm)
      #pragma unroll
      for (int i = 0; i < 4; ++i)
        pl[w][fm * 16 + g * 4 + i] = ps[fm][i];
  }
  __syncthreads();
  if (tid < 128){
    int rr = tid;
    int wrr = rr >> 6, lr = rr & 63;
    float sum = pl[wrr * 4 + 0][lr] + pl[wrr * 4 + 1][lr] + pl[wrr * 4 + 2][lr] + pl[wrr * 4 + 3][lr];
    out[(size_t)t * VOCAB_ + vbase + rr] = sum * (1.0f / 256.0f);
  }
}

// ---------------- host ----------------
extern "C" void kernel_launch(void* const* d_in, const int* in_sizes, int n_in,
                              void* d_out, int out_size, void* d_ws, size_t ws_size,
                              hipStream_t stream){
  const int*   tokens = (const int*)d_in[0];
  const float* E      = (const float*)d_in[1];
  const float* W      = (const float*)d_in[2];
  const float* mdbp   = (const float*)d_in[3];
  const float* nsp    = (const float*)d_in[4];
  float* out = (float*)d_out;
  float* ws  = (float*)d_ws;
  if (ws_size < WS_FLOATS * sizeof(float)) return;   // insufficient scratch -> clean fail

  k0_init<<<dim3(32000), dim3(256), 0, stream>>>(E, ws);
  k_wbar<<<dim3(256), dim3(256), 0, stream>>>(W, ws);
  k_xm<<<dim3(1), dim3(1024), 0, stream>>>(tokens, E, mdbp, nsp, ws);
  k_measall<<<dim3(256), dim3(256), 0, stream>>>(W, ws);
  {
    void* args[1];
    args[0] = (void*)&ws;
    hipLaunchCooperativeKernel((const void*)k_stats, dim3(64), dim3(1024), args, 0, stream);
  }
  k_rho<<<dim3(64, 8), dim3(256), 0, stream>>>(ws);
  k_tri<<<dim3(64), dim3(1024), 0, stream>>>(ws);
  k_bisect<<<dim3(64), dim3(256), 0, stream>>>(ws, out);
  k_gemm<<<dim3(250, 64), dim3(512), 0, stream>>>(ws, out);
}

// Round 9
// 3181.908 us; speedup vs baseline: 1.2335x; 1.2335x over previous
//
#include <hip/hip_runtime.h>
#include <hip/hip_bf16.h>
#include <cstdint>
#include <cstddef>

// ---------------- ws layout (float offsets) ----------------
constexpr size_t OFF_MEM    = 0;          // 65536   (unused; layout kept)
constexpr size_t OFF_XM     = 65536;      // 16384   xm[d][t] transposed (d*64+t)
constexpr size_t OFF_MU     = 82176;      // 16384   mu[t][d]
constexpr size_t OFF_SABS   = 98560;      // 64*4    per-step surprise sums (3 frames)
constexpr size_t OFF_BAR    = 98816;      // 1       grid-barrier epoch counter (zeroed by k0)
constexpr size_t ZERO_END   = 98880;
constexpr size_t OFF_WBAR   = 98880;      // 65536   Wbar = mean_n W  [d][e]
constexpr size_t OFF_MEANS  = 164416;     // (unused; layout kept)
constexpr size_t OFF_VARS   = 361024;     // (unused; layout kept)
constexpr size_t OFF_DT     = 557632;     // 64*256  tridiagonal diag
constexpr size_t OFF_ET     = 574016;     // 64*256  tridiagonal offdiag
constexpr size_t OFF_RHO    = 590400;     // 64*65536: meas[n][t][e] first, then rho[t] (aliased)
constexpr size_t OFF_MN16   = 4784704;    // bf16 mn [64][256][256] = 2097152 floats
constexpr size_t OFF_E16    = 6881856;    // bf16 E  [32000][256]  = 4096000 floats
constexpr size_t WS_FLOATS  = 10977856;   // ~41.9 MiB

#define SEQ_ 64
#define VOCAB_ 32000

typedef __attribute__((ext_vector_type(8))) short bf16x8;
typedef __attribute__((ext_vector_type(4))) float f32x4;

// ---------------- reduction helpers ----------------
__device__ __forceinline__ float wave_sum(float v){
  v += __shfl_xor(v, 32); v += __shfl_xor(v, 16); v += __shfl_xor(v, 8);
  v += __shfl_xor(v, 4);  v += __shfl_xor(v, 2);  v += __shfl_xor(v, 1);
  return v;
}
__device__ __forceinline__ float block_sum(float v, float* red){
  int tid = threadIdx.x;
  v = wave_sum(v);
  if ((tid & 63) == 0) red[tid >> 6] = v;
  __syncthreads();
  float r = red[0] + red[1] + red[2] + red[3];
  __syncthreads();
  return r;
}
__device__ __forceinline__ float block_min(float v, float* red){
  int tid = threadIdx.x;
  v = fminf(v, __shfl_xor(v, 32)); v = fminf(v, __shfl_xor(v, 16));
  v = fminf(v, __shfl_xor(v, 8));  v = fminf(v, __shfl_xor(v, 4));
  v = fminf(v, __shfl_xor(v, 2));  v = fminf(v, __shfl_xor(v, 1));
  if ((tid & 63) == 0) red[tid >> 6] = v;
  __syncthreads();
  float r = fminf(fminf(red[0], red[1]), fminf(red[2], red[3]));
  __syncthreads();
  return r;
}
__device__ __forceinline__ float block_max(float v, float* red){
  int tid = threadIdx.x;
  v = fmaxf(v, __shfl_xor(v, 32)); v = fmaxf(v, __shfl_xor(v, 16));
  v = fmaxf(v, __shfl_xor(v, 8));  v = fmaxf(v, __shfl_xor(v, 4));
  v = fmaxf(v, __shfl_xor(v, 2));  v = fmaxf(v, __shfl_xor(v, 1));
  if ((tid & 63) == 0) red[tid >> 6] = v;
  __syncthreads();
  float r = fmaxf(fmaxf(red[0], red[1]), fmaxf(red[2], red[3]));
  __syncthreads();
  return r;
}

// ---------------- K0: zero state + E -> bf16 ----------------
__global__ __launch_bounds__(256) void k0_init(const float* __restrict__ E, float* __restrict__ ws){
  size_t i = (size_t)blockIdx.x * 256 + threadIdx.x;   // exactly 8,192,000 threads
  if (i < ZERO_END) ws[i] = 0.f;
  __hip_bfloat16* e16 = (__hip_bfloat16*)(ws + OFF_E16);
  e16[i] = __float2bfloat16(E[i]);
}

// ---------------- K_wbar: Wbar[d][e] = mean_n W[n][d][e] ----------------
__global__ __launch_bounds__(256) void k_wbar(const float* __restrict__ W, float* __restrict__ ws){
  size_t i = (size_t)blockIdx.x * 256 + threadIdx.x;   // 65536 threads
  float s = 0.f;
  #pragma unroll 4
  for (int n = 0; n < 256; ++n)
    s += W[(size_t)n * 65536 + i];
  ws[OFF_WBAR + i] = s * (1.0f / 256.0f);
}

// ---------------- K_xm: sequential scalar recurrence (1 block, 1024 threads) ----------------
__global__ __launch_bounds__(1024) void k_xm(const int* __restrict__ tokens,
    const float* __restrict__ E, const float* __restrict__ mdbp,
    const float* __restrict__ nsp, float* __restrict__ ws){
  __shared__ float xm_s[256];
  __shared__ __align__(16) float part[4][256];
  __shared__ float redA[16], redB[16], redC[16];
  const int tid = threadIdx.x;
  const int e = tid & 255, q = tid >> 8;
  const int lane = tid & 63, w = tid >> 6;
  const float sens = fabsf(nsp[0]);
  const float mdb  = mdbp[0];
  const float* Wb = ws + OFF_WBAR;
  float mm = 0.f;                                    // valid on tid<256; 0 elsewhere

  for (int t = 0; t < SEQ_; ++t){
    int tok = tokens[t];
    float xv = (tid < 256) ? E[(size_t)tok * 256 + e] : 0.f;
    float a = wave_sum(xv * mm);
    float b = wave_sum(xv * xv);
    float c = wave_sum(mm * mm);
    if (lane == 0){ redA[w] = a; redB[w] = b; redC[w] = c; }
    __syncthreads();                                 // S1: partials ready
    float sdot = (redA[0] + redA[1]) + (redA[2] + redA[3]);
    float sx2  = (redB[0] + redB[1]) + (redB[2] + redB[3]);
    float sm2  = (redC[0] + redC[1]) + (redC[2] + redC[3]);
    float mem_norm = sqrtf(sm2) + 1e-10f;
    float x_norm   = sqrtf(sx2) + 1e-10f;
    float novelty = (mem_norm > 1e-8f) ? (1.0f - sdot / (x_norm * mem_norm)) : 1.0f;
    float z = mdb - sens * novelty;
    float decay = 1.0f / (1.0f + expf(-z));
    if (tid < 256){
      float xmv = xv + decay * mm;
      xm_s[e] = xmv;
      ws[OFF_XM + (size_t)e * 64 + t] = xmv;         // transposed for k_measall
    }
    __syncthreads();                                 // S2: xm_s ready

    const float* Wq = Wb + (size_t)(q * 64) * 256 + e;
    float p = 0.f;
    #pragma unroll 16
    for (int dd = 0; dd < 64; ++dd)
      p = fmaf(xm_s[q * 64 + dd], Wq[(size_t)dd * 256], p);
    part[q][e] = p;
    __syncthreads();                                 // S3: partials ready
    if (tid < 256){
      float acc = (part[0][e] + part[1][e]) + (part[2][e] + part[3][e]);
      ws[OFF_MU + (size_t)t * 256 + e] = acc;
      mm = decay * mm + (1.0f - decay) * acc;
    }
    __syncthreads();                                 // S4: reuse guard
  }
}

// ---------------- K_measall: meas[n][t][e] = sum_d xm[t][d] W[n][d][e] ----------------
__global__ __launch_bounds__(256) void k_measall(const float* __restrict__ W, float* __restrict__ ws){
  __shared__ __align__(16) float xm_s[16384];        // [d][t] (d*64+t)
  const int tid = threadIdx.x, n = blockIdx.x;
  for (int i = tid; i < 16384; i += 256) xm_s[i] = ws[OFF_XM + i];
  __syncthreads();

  float acc[64];
  #pragma unroll
  for (int t = 0; t < 64; ++t) acc[t] = 0.f;

  const float* Wn = W + (size_t)n * 65536 + tid;
  for (int d = 0; d < 256; ++d){
    float wv = Wn[(size_t)d * 256];
    const float* xr = &xm_s[d * 64];
    #pragma unroll
    for (int q = 0; q < 16; ++q){
      float4 x4 = *(const float4*)&xr[q * 4];
      acc[q * 4 + 0] = fmaf(x4.x, wv, acc[q * 4 + 0]);
      acc[q * 4 + 1] = fmaf(x4.y, wv, acc[q * 4 + 1]);
      acc[q * 4 + 2] = fmaf(x4.z, wv, acc[q * 4 + 2]);
      acc[q * 4 + 3] = fmaf(x4.w, wv, acc[q * 4 + 3]);
    }
  }
  #pragma unroll
  for (int t = 0; t < 64; ++t)
    ws[OFF_RHO + (size_t)n * 16384 + (size_t)t * 256 + tid] = acc[t];
}

// ---------------- K_stats: sequential know/means/vars recurrence ----------------
__global__ __launch_bounds__(1024, 1) void k_stats(float* __restrict__ ws){
  __shared__ float redA[16], redB[16], redC[16];
  const int tid = threadIdx.x;
  const int e = tid & 255, q = tid >> 8;
  const int lane = tid & 63, w = tid >> 6;
  const int n = blockIdx.x * 4 + q;
  unsigned* bar = (unsigned*)(ws + OFF_BAR);
  __hip_bfloat16* mn16 = (__hip_bfloat16*)(ws + OFF_MN16);
  const size_t ne = (size_t)n * 256 + e;
  const float TH = 1.5f * 65536.0f;
  const float c5 = 0.59049f;                         // 0.9^5

  float mean0 = 0.f, mean1 = 0.f, mean2 = 0.f;
  float var0 = 0.f, var1 = 0.f, var2 = 0.f;

  for (int t = 0; t < SEQ_; ++t){
    float me = ws[OFF_RHO + (size_t)n * 16384 + (size_t)t * 256 + e];
    bool know = false;
    if (t > 0){
      float v0 = fabsf(me - mean0) / sqrtf(var0 + 1e-8f);
      float v1 = fabsf(me - mean1) / sqrtf(var1 + 1e-8f);
      float v2 = fabsf(me - mean2) / sqrtf(var2 + 1e-8f);
      float a = wave_sum(v0), b = wave_sum(v1), c = wave_sum(v2);
      if (lane == 0){ redA[w] = a; redB[w] = b; redC[w] = c; }
      __syncthreads();                               // S1: partials ready
      if (tid == 0){
        float sA = 0.f, sB = 0.f, sC = 0.f;
        #pragma unroll
        for (int i = 0; i < 16; ++i){ sA += redA[i]; sB += redB[i]; sC += redC[i]; }
        atomicAdd(&ws[OFF_SABS + (size_t)t * 4 + 0], sA);
        atomicAdd(&ws[OFF_SABS + (size_t)t * 4 + 1], sB);
        atomicAdd(&ws[OFF_SABS + (size_t)t * 4 + 2], sC);
        __hip_atomic_fetch_add(bar, 1u, __ATOMIC_ACQ_REL, __HIP_MEMORY_SCOPE_AGENT);
        unsigned tgt = 64u * (unsigned)t;
        while (__hip_atomic_load(bar, __ATOMIC_ACQUIRE, __HIP_MEMORY_SCOPE_AGENT) < tgt)
          __builtin_amdgcn_s_sleep(2);
      }
      __syncthreads();                               // S2: sabs complete everywhere
      float s0 = __hip_atomic_load(&ws[OFF_SABS + (size_t)t * 4 + 0], __ATOMIC_RELAXED, __HIP_MEMORY_SCOPE_AGENT);
      float s1 = __hip_atomic_load(&ws[OFF_SABS + (size_t)t * 4 + 1], __ATOMIC_RELAXED, __HIP_MEMORY_SCOPE_AGENT);
      float s2 = __hip_atomic_load(&ws[OFF_SABS + (size_t)t * 4 + 2], __ATOMIC_RELAXED, __HIP_MEMORY_SCOPE_AGENT);
      know = (s0 < TH) || (s1 < TH) || (s2 < TH);
    }
    float mu = ws[OFF_MU + (size_t)t * 256 + e];
    float eq = c5 * me + (1.0f - c5) * mu;
    float eff = know ? me : eq;

    if (t == 0){
      mean0 = eff; mean1 = eff; mean2 = eff;
      var0 = 0.1f; var1 = 0.1f; var2 = 0.1f;
    } else {
      float um, uv;
      um = 0.3f * mean0 + 0.7f * eff;
      uv = 0.3f * var0 + 0.7f * (eff - mean0) * (eff - um);
      mean0 = um; var0 = fmaxf(uv, 1e-8f);
      um = 0.7f * mean1 + 0.3f * eff;
      uv = 0.7f * var1 + 0.3f * (eff - mean1) * (eff - um);
      mean1 = um; var1 = fmaxf(uv, 1e-8f);
      um = 0.9f * mean2 + 0.1f * eff;
      uv = 0.9f * var2 + 0.1f * (eff - mean2) * (eff - um);
      mean2 = um; var2 = fmaxf(uv, 1e-8f);
    }

    float nv = wave_sum(eff * eff);
    if (lane == 0) redA[w] = nv;
    __syncthreads();                                 // S3: quarter partials
    float nr2 = (redA[4 * q + 0] + redA[4 * q + 1]) + (redA[4 * q + 2] + redA[4 * q + 3]);
    float rn = sqrtf(nr2) + 1e-10f;
    mn16[(size_t)t * 65536 + ne] = __float2bfloat16(eff / rn);
    __syncthreads();                                 // S4: red reuse guard
  }
}

// ---------------- K_rho: rho[t] = mn^T mn / NB (fp32 accum from bf16) ----------------
__global__ __launch_bounds__(256) void k_rho(float* __restrict__ ws){
  const int t = blockIdx.x, rb = blockIdx.y, tid = threadIdx.x;
  __shared__ __align__(16) float tile[32][256];
  const __hip_bfloat16* mn16 = (const __hip_bfloat16*)(ws + OFF_MN16);
  float acc[32];
  #pragma unroll
  for (int i = 0; i < 32; ++i) acc[i] = 0.f;
  for (int c = 0; c < 8; ++c){
    __syncthreads();
    for (int j = tid; j < 8192; j += 256){
      int row = j >> 8, col = j & 255;
      tile[row][col] = __bfloat162float(mn16[(size_t)t * 65536 + (size_t)(c * 32 + row) * 256 + col]);
    }
    __syncthreads();
    for (int nl = 0; nl < 32; ++nl){
      float ev = tile[nl][tid];
      #pragma unroll
      for (int q = 0; q < 8; ++q){
        float4 dv = *(const float4*)&tile[nl][rb * 32 + q * 4];
        acc[q * 4 + 0] = fmaf(dv.x, ev, acc[q * 4 + 0]);
        acc[q * 4 + 1] = fmaf(dv.y, ev, acc[q * 4 + 1]);
        acc[q * 4 + 2] = fmaf(dv.z, ev, acc[q * 4 + 2]);
        acc[q * 4 + 3] = fmaf(dv.w, ev, acc[q * 4 + 3]);
      }
    }
  }
  #pragma unroll
  for (int i = 0; i < 32; ++i)
    ws[OFF_RHO + (size_t)t * 65536 + (size_t)(rb * 32 + i) * 256 + tid] = acc[i] * (1.0f / 256.0f);
}

// ---------------- K_trigemm: fused k_tri (blocks 0..63) + k_gemm (blocks 64..16063) ----------------
// k_tri is latency-bound (6% VALUBusy) and occupies <=64 CUs for ~1.9ms with the
// rest of the chip idle; k_gemm depends only on mn16/E16 (not on k_tri). Fusing
// them into one launch overlaps gemm's MFMA work into tri's shadow. Tri blocks
// dispatch first (resident immediately). LDS: one 51.2KB raw array aliased by
// path (tri uses 5.2KB of it). Tri body is the PROVEN (512,2)/Mreg[128] 7-barrier
// kernel, byte-identical logic.
__global__ __launch_bounds__(512, 2) void k_trigemm(float* __restrict__ ws, float* __restrict__ out){
  __shared__ __align__(16) char smem_raw[51200];
  const int tid = threadIdx.x;

  if (blockIdx.x < 64){
    // ================= TRI PATH =================
    float* ca   = (float*)smem_raw;          // 256
    float* ua   = ca + 256;                  // 256
    float* wa   = ua + 256;                  // 256
    float* ph   = wa + 256;                  // 512
    float* redA = ph + 512;                  // 8
    float* redB = redA + 8;                  // 8
    const int t = blockIdx.x;
    const int c = tid & 255, h = tid >> 8;
    const float* rho = ws + OFF_RHO + (size_t)t * 65536;
    float* dT = ws + OFF_DT + (size_t)t * 256;
    float* eT = ws + OFF_ET + (size_t)t * 256;

    float Mreg[128];
    {
      const float* Mc = rho + (size_t)(h * 128) * 256 + c;
      #pragma unroll
      for (int rr = 0; rr < 128; ++rr)
        Mreg[rr] = Mc[(size_t)rr * 256];
    }
    const int rowbase = h * 128;

    for (int k = 0; k < 254; ++k){
      __syncthreads();                                // S1: prev update done
      if (c == k){
        #pragma unroll
        for (int rr = 0; rr < 128; ++rr) ca[rowbase + rr] = Mreg[rr];
      }
      __syncthreads();                                // S2: ca visible
      float uval = 0.f;
      if (tid < 256){
        float raw = ca[tid];
        uval = (tid > k) ? raw : 0.f;
        ua[tid] = uval;
        if (tid == 0) dT[k] = ca[k];
      }
      float pa = wave_sum(uval * uval);
      if ((tid & 63) == 0) redA[tid >> 6] = pa;
      __syncthreads();                                // S3: ua + redA
      float sigma2 = redA[0] + redA[1] + redA[2] + redA[3]
                   + redA[4] + redA[5] + redA[6] + redA[7];
      float v0 = ca[k + 1];
      if (sigma2 < 1e-30f){                           // uniform branch
        if (tid == 0) eT[k] = v0;
        continue;                                     // H = I
      }
      float sig = sqrtf(sigma2);
      float alpha = (v0 >= 0.f) ? -sig : sig;
      float u0 = v0 - alpha;
      float beta = 2.0f / (sigma2 - v0 * v0 + u0 * u0);
      if (tid == 0) eT[k] = alpha;
      if (tid == k + 1) ua[tid] = u0;
      __syncthreads();                                // S4: u final

      {
        float a0 = 0.f, a1 = 0.f, a2 = 0.f, a3 = 0.f;
        #pragma unroll
        for (int rr = 0; rr < 128; rr += 4){
          float4 u4 = *(const float4*)&ua[rowbase + rr];
          a0 = fmaf(Mreg[rr + 0], u4.x, a0);
          a1 = fmaf(Mreg[rr + 1], u4.y, a1);
          a2 = fmaf(Mreg[rr + 2], u4.z, a2);
          a3 = fmaf(Mreg[rr + 3], u4.w, a3);
        }
        ph[tid] = (a0 + a1) + (a2 + a3);
      }
      __syncthreads();                                // S5: ph
      float p = ph[c] + ph[c + 256];                  // (A u)_c
      float up = (tid < 256) ? ua[tid] * p : 0.f;
      float pb = wave_sum(up);
      if ((tid & 63) == 0) redB[tid >> 6] = pb;
      __syncthreads();                                // S6: redB
      float s = redB[0] + redB[1] + redB[2] + redB[3]
              + redB[4] + redB[5] + redB[6] + redB[7];
      if (tid < 256) wa[tid] = (tid > k) ? (beta * p - 0.5f * beta * beta * s * ua[tid]) : 0.f;
      __syncthreads();                                // S7: wa
      {
        float ucv = ua[c], wcv = wa[c];
        #pragma unroll
        for (int rr = 0; rr < 128; rr += 4){
          float4 u4 = *(const float4*)&ua[rowbase + rr];
          float4 w4 = *(const float4*)&wa[rowbase + rr];
          Mreg[rr + 0] = fmaf(-w4.x, ucv, fmaf(-u4.x, wcv, Mreg[rr + 0]));
          Mreg[rr + 1] = fmaf(-w4.y, ucv, fmaf(-u4.y, wcv, Mreg[rr + 1]));
          Mreg[rr + 2] = fmaf(-w4.z, ucv, fmaf(-u4.z, wcv, Mreg[rr + 2]));
          Mreg[rr + 3] = fmaf(-w4.w, ucv, fmaf(-u4.w, wcv, Mreg[rr + 3]));
        }
      }
    }

    // tail: dT[254], dT[255], eT[254]
    __syncthreads();
    if (c == 254){
      #pragma unroll
      for (int rr = 0; rr < 128; ++rr) ca[rowbase + rr] = Mreg[rr];
    }
    __syncthreads();
    if (tid == 0){ dT[254] = ca[254]; eT[254] = ca[255]; }
    __syncthreads();
    if (c == 255){
      #pragma unroll
      for (int rr = 0; rr < 128; ++rr) ca[rowbase + rr] = Mreg[rr];
    }
    __syncthreads();
    if (tid == 0){ dT[255] = ca[255]; eT[255] = 0.f; }
  } else {
    // ================= GEMM PATH =================
    short* A_lds = (short*)smem_raw;                 // [128 v][8 chunks of 8]
    short* B_lds = A_lds + 8192;                     // [256 n][8 chunks of 8]
    float* pl    = (float*)(B_lds + 16384);          // [8][64]
    const int g = blockIdx.x - 64;
    const int bx = g % 250, t = g / 250;
    const int lane = tid & 63, w = tid >> 6;
    const int wr = w >> 2, wc = w & 3;
    const int vbase = bx * 128;
    const short* E16 = (const short*)(ws + OFF_E16);
    const short* MN  = (const short*)(ws + OFF_MN16) + (size_t)t * 65536;

    f32x4 acc[4][4];
    #pragma unroll
    for (int i = 0; i < 4; ++i)
      #pragma unroll
      for (int j = 0; j < 4; ++j){ f32x4 z = {0.f, 0.f, 0.f, 0.f}; acc[i][j] = z; }

    const int gq = lane >> 4, r16 = lane & 15;
    const int sx = r16 & 7;                          // read-side XOR key
    for (int it = 0; it < 4; ++it){
      const int k0 = it * 64;
      __syncthreads();
      #pragma unroll
      for (int pa = 0; pa < 2; ++pa){
        int ch = pa * 512 + tid;
        int row = ch >> 3, c8 = ch & 7;
        int sc8 = c8 ^ (row & 7);                    // pre-swizzled source chunk
        uint4 v = *(const uint4*)(E16 + (size_t)(vbase + row) * 256 + k0 + sc8 * 8);
        *(uint4*)&A_lds[ch * 8] = v;                 // linear dest (conflict-free)
      }
      #pragma unroll
      for (int pb = 0; pb < 4; ++pb){
        int ch = pb * 512 + tid;
        int row = ch >> 3, c8 = ch & 7;
        int sc8 = c8 ^ (row & 7);
        uint4 v = *(const uint4*)(MN + (size_t)row * 256 + k0 + sc8 * 8);
        *(uint4*)&B_lds[ch * 8] = v;
      }
      __syncthreads();
      #pragma unroll
      for (int kk = 0; kk < 64; kk += 32){
        const int j0 = (kk >> 3) + gq;               // logical chunk index
        bf16x8 af[4], bf[4];
        #pragma unroll
        for (int fm = 0; fm < 4; ++fm)
          af[fm] = *(const bf16x8*)&A_lds[(wr * 64 + fm * 16 + r16) * 64 + (j0 ^ sx) * 8];
        #pragma unroll
        for (int fn = 0; fn < 4; ++fn)
          bf[fn] = *(const bf16x8*)&B_lds[(wc * 64 + fn * 16 + r16) * 64 + (j0 ^ sx) * 8];
        #pragma unroll
        for (int fm = 0; fm < 4; ++fm)
          #pragma unroll
          for (int fn = 0; fn < 4; ++fn)
            acc[fm][fn] = __builtin_amdgcn_mfma_f32_16x16x32_bf16(af[fm], bf[fn], acc[fm][fn], 0, 0, 0);
      }
    }

    // epilogue: square + reduce over n
    float ps[4][4];
    #pragma unroll
    for (int fm = 0; fm < 4; ++fm)
      #pragma unroll
      for (int i = 0; i < 4; ++i){
        float sv = 0.f;
        #pragma unroll
        for (int fn = 0; fn < 4; ++fn){ float v = acc[fm][fn][i]; sv += v * v; }
        sv += __shfl_xor(sv, 1); sv += __shfl_xor(sv, 2);
        sv += __shfl_xor(sv, 4); sv += __shfl_xor(sv, 8);
        ps[fm][i] = sv;
      }
    __syncthreads();
    if (r16 == 0){
      #pragma unroll
      for (int fm = 0; fm < 4; ++fm)
        #pragma unroll
        for (int i = 0; i < 4; ++i)
          pl[w * 64 + fm * 16 + gq * 4 + i] = ps[fm][i];
    }
    __syncthreads();
    if (tid < 128){
      int rr = tid;
      int wrr = rr >> 6, lr = rr & 63;
      float sum = pl[(wrr * 4 + 0) * 64 + lr] + pl[(wrr * 4 + 1) * 64 + lr]
                + pl[(wrr * 4 + 2) * 64 + lr] + pl[(wrr * 4 + 3) * 64 + lr];
      out[(size_t)t * VOCAB_ + vbase + rr] = sum * (1.0f / 256.0f);
    }
  }
}

// ---------------- K_bisect: Sturm bisection, one eigenvalue per thread ----------------
__global__ __launch_bounds__(256) void k_bisect(const float* __restrict__ ws, float* __restrict__ out){
  __shared__ float d_s[256];
  __shared__ float e2_s[256];
  __shared__ float ea_s[256];
  __shared__ float red[4];
  const int t = blockIdx.x, tid = threadIdx.x;
  d_s[tid] = ws[OFF_DT + (size_t)t * 256 + tid];
  float evv = (tid < 255) ? ws[OFF_ET + (size_t)t * 256 + tid] : 0.f;
  e2_s[tid] = evv * evv;
  ea_s[tid] = fabsf(evv);
  __syncthreads();
  float rad = ea_s[tid] + ((tid > 0) ? ea_s[tid - 1] : 0.f);
  float glo = block_min(d_s[tid] - rad, red);
  float ghi = block_max(d_s[tid] + rad, red);

  float l = glo, h = ghi;
  for (int it = 0; it < 40; ++it){
    float mid = 0.5f * (l + h);
    float q = d_s[0] - mid;
    int cnt = (q < 0.f) ? 1 : 0;
    #pragma unroll 8
    for (int i = 1; i < 256; ++i){
      float qr = __builtin_amdgcn_rcpf(q);
      q = (d_s[i] - mid) - e2_s[i - 1] * qr;
      q = (fabsf(q) < 1e-25f) ? -1e-25f : q;
      cnt += (q < 0.f) ? 1 : 0;
    }
    if (cnt <= tid) l = mid; else h = mid;
  }
  float lam = fmaxf(0.5f * (l + h), 1e-12f);
  float ssum = block_sum(lam, red);
  out[(size_t)SEQ_ * VOCAB_ + (size_t)t * 256 + tid] = lam / ssum;
}

// ---------------- host ----------------
extern "C" void kernel_launch(void* const* d_in, const int* in_sizes, int n_in,
                              void* d_out, int out_size, void* d_ws, size_t ws_size,
                              hipStream_t stream){
  const int*   tokens = (const int*)d_in[0];
  const float* E      = (const float*)d_in[1];
  const float* W      = (const float*)d_in[2];
  const float* mdbp   = (const float*)d_in[3];
  const float* nsp    = (const float*)d_in[4];
  float* out = (float*)d_out;
  float* ws  = (float*)d_ws;
  if (ws_size < WS_FLOATS * sizeof(float)) return;   // insufficient scratch -> clean fail

  k0_init<<<dim3(32000), dim3(256), 0, stream>>>(E, ws);
  k_wbar<<<dim3(256), dim3(256), 0, stream>>>(W, ws);
  k_xm<<<dim3(1), dim3(1024), 0, stream>>>(tokens, E, mdbp, nsp, ws);
  k_measall<<<dim3(256), dim3(256), 0, stream>>>(W, ws);
  {
    void* args[1];
    args[0] = (void*)&ws;
    hipLaunchCooperativeKernel((const void*)k_stats, dim3(64), dim3(1024), args, 0, stream);
  }
  k_rho<<<dim3(64, 8), dim3(256), 0, stream>>>(ws);
  k_trigemm<<<dim3(64 + 250 * 64), dim3(512), 0, stream>>>(ws, out);
  k_bisect<<<dim3(64), dim3(256), 0, stream>>>(ws, out);
}

// Round 10
// 3104.221 us; speedup vs baseline: 1.2644x; 1.0250x over previous
//
#include <hip/hip_runtime.h>
#include <hip/hip_bf16.h>
#include <cstdint>
#include <cstddef>

// ---------------- ws layout (float offsets) ----------------
constexpr size_t OFF_MEM    = 0;          // 65536   (unused; layout kept)
constexpr size_t OFF_XM     = 65536;      // 16384   xm[d][t] transposed (d*64+t)
constexpr size_t OFF_MU     = 82176;      // 16384   mu[t][d]
constexpr size_t OFF_SABS   = 98560;      // 64*4    per-step surprise sums (3 frames)
constexpr size_t OFF_BAR    = 98816;      // 1       grid-barrier epoch counter (zeroed by k0)
constexpr size_t ZERO_END   = 98880;
constexpr size_t OFF_WBAR   = 98880;      // 65536   Wbar = mean_n W  [d][e]
constexpr size_t OFF_MEANS  = 164416;     // (unused; layout kept)
constexpr size_t OFF_VARS   = 361024;     // (unused; layout kept)
constexpr size_t OFF_DT     = 557632;     // (unused; bisect folded into trigemm)
constexpr size_t OFF_ET     = 574016;     // (unused)
constexpr size_t OFF_RHO    = 590400;     // 64*65536: meas[n][t][e] first, then rho[t] (aliased)
constexpr size_t OFF_MN16   = 4784704;    // bf16 mn [64][256][256] = 2097152 floats
constexpr size_t OFF_E16    = 6881856;    // bf16 E  [32000][256]  = 4096000 floats
constexpr size_t WS_FLOATS  = 10977856;   // ~41.9 MiB

#define SEQ_ 64
#define VOCAB_ 32000

typedef __attribute__((ext_vector_type(8))) short bf16x8;
typedef __attribute__((ext_vector_type(4))) float f32x4;

// ---------------- reduction helpers ----------------
__device__ __forceinline__ float wave_sum(float v){
  v += __shfl_xor(v, 32); v += __shfl_xor(v, 16); v += __shfl_xor(v, 8);
  v += __shfl_xor(v, 4);  v += __shfl_xor(v, 2);  v += __shfl_xor(v, 1);
  return v;
}
__device__ __forceinline__ float block_sum(float v, float* red){
  int tid = threadIdx.x;
  v = wave_sum(v);
  if ((tid & 63) == 0) red[tid >> 6] = v;
  __syncthreads();
  float r = red[0] + red[1] + red[2] + red[3];
  __syncthreads();
  return r;
}

// ---------------- K0: zero state + E -> bf16 ----------------
__global__ __launch_bounds__(256) void k0_init(const float* __restrict__ E, float* __restrict__ ws){
  size_t i = (size_t)blockIdx.x * 256 + threadIdx.x;   // exactly 8,192,000 threads
  if (i < ZERO_END) ws[i] = 0.f;
  __hip_bfloat16* e16 = (__hip_bfloat16*)(ws + OFF_E16);
  e16[i] = __float2bfloat16(E[i]);
}

// ---------------- K_wbar: Wbar[d][e] = mean_n W[n][d][e] ----------------
__global__ __launch_bounds__(256) void k_wbar(const float* __restrict__ W, float* __restrict__ ws){
  size_t i = (size_t)blockIdx.x * 256 + threadIdx.x;   // 65536 threads
  float s = 0.f;
  #pragma unroll 4
  for (int n = 0; n < 256; ++n)
    s += W[(size_t)n * 65536 + i];
  ws[OFF_WBAR + i] = s * (1.0f / 256.0f);
}

// ---------------- K_xm: sequential scalar recurrence (1 block, 1024 threads) ----------------
// Wbar quarter-column held in 64 REGISTERS per thread (t-invariant; loaded once)
// -> per-step matvec is pure LDS+FMA, no L2 loads in the serial chain.
__global__ __launch_bounds__(1024, 1) void k_xm(const int* __restrict__ tokens,
    const float* __restrict__ E, const float* __restrict__ mdbp,
    const float* __restrict__ nsp, float* __restrict__ ws){
  __shared__ float xm_s[256];
  __shared__ __align__(16) float part[4][256];
  __shared__ float redA[16], redB[16], redC[16];
  const int tid = threadIdx.x;
  const int e = tid & 255, q = tid >> 8;
  const int lane = tid & 63, w = tid >> 6;
  const float sens = fabsf(nsp[0]);
  const float mdb  = mdbp[0];
  const float* Wb = ws + OFF_WBAR;
  float mm = 0.f;                                    // valid on tid<256; 0 elsewhere

  // preload my Wbar quarter-column: wreg[dd] = Wbar[q*64+dd][e]
  float wreg[64];
  {
    const float* Wq = Wb + (size_t)(q * 64) * 256 + e;
    #pragma unroll
    for (int dd = 0; dd < 64; ++dd)
      wreg[dd] = Wq[(size_t)dd * 256];
  }

  for (int t = 0; t < SEQ_; ++t){
    int tok = tokens[t];
    float xv = (tid < 256) ? E[(size_t)tok * 256 + e] : 0.f;
    float a = wave_sum(xv * mm);
    float b = wave_sum(xv * xv);
    float c = wave_sum(mm * mm);
    if (lane == 0){ redA[w] = a; redB[w] = b; redC[w] = c; }
    __syncthreads();                                 // S1: partials ready
    float sdot = (redA[0] + redA[1]) + (redA[2] + redA[3]);
    float sx2  = (redB[0] + redB[1]) + (redB[2] + redB[3]);
    float sm2  = (redC[0] + redC[1]) + (redC[2] + redC[3]);
    float mem_norm = sqrtf(sm2) + 1e-10f;
    float x_norm   = sqrtf(sx2) + 1e-10f;
    float novelty = (mem_norm > 1e-8f) ? (1.0f - sdot / (x_norm * mem_norm)) : 1.0f;
    float z = mdb - sens * novelty;
    float decay = 1.0f / (1.0f + expf(-z));
    if (tid < 256){
      float xmv = xv + decay * mm;
      xm_s[e] = xmv;
      ws[OFF_XM + (size_t)e * 64 + t] = xmv;         // transposed for k_measall
    }
    __syncthreads();                                 // S2: xm_s ready

    float p = 0.f;
    #pragma unroll
    for (int dd = 0; dd < 64; ++dd)
      p = fmaf(xm_s[q * 64 + dd], wreg[dd], p);
    part[q][e] = p;
    __syncthreads();                                 // S3: partials ready
    if (tid < 256){
      float acc = (part[0][e] + part[1][e]) + (part[2][e] + part[3][e]);
      ws[OFF_MU + (size_t)t * 256 + e] = acc;
      mm = decay * mm + (1.0f - decay) * acc;
    }
    __syncthreads();                                 // S4: reuse guard
  }
}

// ---------------- K_measall: meas[n][t][e] = sum_d xm[t][d] W[n][d][e] ----------------
__global__ __launch_bounds__(256) void k_measall(const float* __restrict__ W, float* __restrict__ ws){
  __shared__ __align__(16) float xm_s[16384];        // [d][t] (d*64+t)
  const int tid = threadIdx.x, n = blockIdx.x;
  for (int i = tid; i < 16384; i += 256) xm_s[i] = ws[OFF_XM + i];
  __syncthreads();

  float acc[64];
  #pragma unroll
  for (int t = 0; t < 64; ++t) acc[t] = 0.f;

  const float* Wn = W + (size_t)n * 65536 + tid;
  for (int d = 0; d < 256; ++d){
    float wv = Wn[(size_t)d * 256];
    const float* xr = &xm_s[d * 64];
    #pragma unroll
    for (int q = 0; q < 16; ++q){
      float4 x4 = *(const float4*)&xr[q * 4];
      acc[q * 4 + 0] = fmaf(x4.x, wv, acc[q * 4 + 0]);
      acc[q * 4 + 1] = fmaf(x4.y, wv, acc[q * 4 + 1]);
      acc[q * 4 + 2] = fmaf(x4.z, wv, acc[q * 4 + 2]);
      acc[q * 4 + 3] = fmaf(x4.w, wv, acc[q * 4 + 3]);
    }
  }
  #pragma unroll
  for (int t = 0; t < 64; ++t)
    ws[OFF_RHO + (size_t)n * 16384 + (size_t)t * 256 + tid] = acc[t];
}

// ---------------- K_stats: sequential know/means/vars recurrence ----------------
__global__ __launch_bounds__(1024, 1) void k_stats(float* __restrict__ ws){
  __shared__ float redA[16], redB[16], redC[16];
  const int tid = threadIdx.x;
  const int e = tid & 255, q = tid >> 8;
  const int lane = tid & 63, w = tid >> 6;
  const int n = blockIdx.x * 4 + q;
  unsigned* bar = (unsigned*)(ws + OFF_BAR);
  __hip_bfloat16* mn16 = (__hip_bfloat16*)(ws + OFF_MN16);
  const size_t ne = (size_t)n * 256 + e;
  const float TH = 1.5f * 65536.0f;
  const float c5 = 0.59049f;                         // 0.9^5

  float mean0 = 0.f, mean1 = 0.f, mean2 = 0.f;
  float var0 = 0.f, var1 = 0.f, var2 = 0.f;

  for (int t = 0; t < SEQ_; ++t){
    float me = ws[OFF_RHO + (size_t)n * 16384 + (size_t)t * 256 + e];
    bool know = false;
    if (t > 0){
      float v0 = fabsf(me - mean0) / sqrtf(var0 + 1e-8f);
      float v1 = fabsf(me - mean1) / sqrtf(var1 + 1e-8f);
      float v2 = fabsf(me - mean2) / sqrtf(var2 + 1e-8f);
      float a = wave_sum(v0), b = wave_sum(v1), c = wave_sum(v2);
      if (lane == 0){ redA[w] = a; redB[w] = b; redC[w] = c; }
      __syncthreads();                               // S1: partials ready
      if (tid == 0){
        float sA = 0.f, sB = 0.f, sC = 0.f;
        #pragma unroll
        for (int i = 0; i < 16; ++i){ sA += redA[i]; sB += redB[i]; sC += redC[i]; }
        atomicAdd(&ws[OFF_SABS + (size_t)t * 4 + 0], sA);
        atomicAdd(&ws[OFF_SABS + (size_t)t * 4 + 1], sB);
        atomicAdd(&ws[OFF_SABS + (size_t)t * 4 + 2], sC);
        __hip_atomic_fetch_add(bar, 1u, __ATOMIC_ACQ_REL, __HIP_MEMORY_SCOPE_AGENT);
        unsigned tgt = 64u * (unsigned)t;
        while (__hip_atomic_load(bar, __ATOMIC_ACQUIRE, __HIP_MEMORY_SCOPE_AGENT) < tgt)
          __builtin_amdgcn_s_sleep(2);
      }
      __syncthreads();                               // S2: sabs complete everywhere
      float s0 = __hip_atomic_load(&ws[OFF_SABS + (size_t)t * 4 + 0], __ATOMIC_RELAXED, __HIP_MEMORY_SCOPE_AGENT);
      float s1 = __hip_atomic_load(&ws[OFF_SABS + (size_t)t * 4 + 1], __ATOMIC_RELAXED, __HIP_MEMORY_SCOPE_AGENT);
      float s2 = __hip_atomic_load(&ws[OFF_SABS + (size_t)t * 4 + 2], __ATOMIC_RELAXED, __HIP_MEMORY_SCOPE_AGENT);
      know = (s0 < TH) || (s1 < TH) || (s2 < TH);
    }
    float mu = ws[OFF_MU + (size_t)t * 256 + e];
    float eq = c5 * me + (1.0f - c5) * mu;
    float eff = know ? me : eq;

    if (t == 0){
      mean0 = eff; mean1 = eff; mean2 = eff;
      var0 = 0.1f; var1 = 0.1f; var2 = 0.1f;
    } else {
      float um, uv;
      um = 0.3f * mean0 + 0.7f * eff;
      uv = 0.3f * var0 + 0.7f * (eff - mean0) * (eff - um);
      mean0 = um; var0 = fmaxf(uv, 1e-8f);
      um = 0.7f * mean1 + 0.3f * eff;
      uv = 0.7f * var1 + 0.3f * (eff - mean1) * (eff - um);
      mean1 = um; var1 = fmaxf(uv, 1e-8f);
      um = 0.9f * mean2 + 0.1f * eff;
      uv = 0.9f * var2 + 0.1f * (eff - mean2) * (eff - um);
      mean2 = um; var2 = fmaxf(uv, 1e-8f);
    }

    float nv = wave_sum(eff * eff);
    if (lane == 0) redA[w] = nv;
    __syncthreads();                                 // S3: quarter partials
    float nr2 = (redA[4 * q + 0] + redA[4 * q + 1]) + (redA[4 * q + 2] + redA[4 * q + 3]);
    float rn = sqrtf(nr2) + 1e-10f;
    mn16[(size_t)t * 65536 + ne] = __float2bfloat16(eff / rn);
    __syncthreads();                                 // S4: red reuse guard
  }
}

// ---------------- K_rho: rho[t] = mn^T mn / NB (fp32 accum from bf16) ----------------
__global__ __launch_bounds__(256) void k_rho(float* __restrict__ ws){
  const int t = blockIdx.x, rb = blockIdx.y, tid = threadIdx.x;
  __shared__ __align__(16) float tile[32][256];
  const unsigned short* mn16 = (const unsigned short*)(ws + OFF_MN16);
  float acc[32];
  #pragma unroll
  for (int i = 0; i < 32; ++i) acc[i] = 0.f;
  for (int c = 0; c < 8; ++c){
    __syncthreads();
    // vectorized: 8192 bf16 per chunk = 1024 uint4; 4 per thread
    #pragma unroll
    for (int v = 0; v < 4; ++v){
      int idx = v * 256 + tid;
      int row = idx >> 5, c16 = idx & 31;
      uint4 u4 = *(const uint4*)(mn16 + (size_t)t * 65536 + (size_t)(c * 32 + row) * 256 + c16 * 8);
      float* dst = &tile[row][c16 * 8];
      unsigned uu[4] = {u4.x, u4.y, u4.z, u4.w};
      #pragma unroll
      for (int j = 0; j < 4; ++j){
        dst[j * 2 + 0] = __uint_as_float(uu[j] << 16);
        dst[j * 2 + 1] = __uint_as_float(uu[j] & 0xffff0000u);
      }
    }
    __syncthreads();
    for (int nl = 0; nl < 32; ++nl){
      float ev = tile[nl][tid];
      #pragma unroll
      for (int q = 0; q < 8; ++q){
        float4 dv = *(const float4*)&tile[nl][rb * 32 + q * 4];
        acc[q * 4 + 0] = fmaf(dv.x, ev, acc[q * 4 + 0]);
        acc[q * 4 + 1] = fmaf(dv.y, ev, acc[q * 4 + 1]);
        acc[q * 4 + 2] = fmaf(dv.z, ev, acc[q * 4 + 2]);
        acc[q * 4 + 3] = fmaf(dv.w, ev, acc[q * 4 + 3]);
      }
    }
  }
  #pragma unroll
  for (int i = 0; i < 32; ++i)
    ws[OFF_RHO + (size_t)t * 65536 + (size_t)(rb * 32 + i) * 256 + tid] = acc[i] * (1.0f / 256.0f);
}

// ---------------- K_trigemm: fused tri+bisect (blocks 0..63) + gemm (blocks 64..16063) ----------------
// Tri path: PROVEN (512,2)/Mreg[128] 7-barrier loop (byte-identical), dd/ee in
// LDS, folded Sturm bisection at the tail (round-2/6-verified code) writing eigs
// directly -> k_bisect launch and dT/eT global round-trip eliminated.
__global__ __launch_bounds__(512, 2) void k_trigemm(float* __restrict__ ws, float* __restrict__ out){
  __shared__ __align__(16) char smem_raw[51200];
  const int tid = threadIdx.x;

  if (blockIdx.x < 64){
    // ================= TRI PATH =================
    float* ca   = (float*)smem_raw;          // 256
    float* ua   = ca + 256;                  // 256
    float* wa   = ua + 256;                  // 256
    float* ph   = wa + 256;                  // 512
    float* redA = ph + 512;                  // 8
    float* redB = redA + 8;                  // 8
    float* dd   = redB + 8;                  // 256
    float* ee   = dd + 256;                  // 256
    const int t = blockIdx.x;
    const int c = tid & 255, h = tid >> 8;
    const int lane = tid & 63, w = tid >> 6;
    const float* rho = ws + OFF_RHO + (size_t)t * 65536;

    float Mreg[128];
    {
      const float* Mc = rho + (size_t)(h * 128) * 256 + c;
      #pragma unroll
      for (int rr = 0; rr < 128; ++rr)
        Mreg[rr] = Mc[(size_t)rr * 256];
    }
    const int rowbase = h * 128;

    for (int k = 0; k < 254; ++k){
      __syncthreads();                                // S1: prev update done
      if (c == k){
        #pragma unroll
        for (int rr = 0; rr < 128; ++rr) ca[rowbase + rr] = Mreg[rr];
      }
      __syncthreads();                                // S2: ca visible
      float uval = 0.f;
      if (tid < 256){
        float raw = ca[tid];
        uval = (tid > k) ? raw : 0.f;
        ua[tid] = uval;
        if (tid == 0) dd[k] = ca[k];
      }
      float pa = wave_sum(uval * uval);
      if ((tid & 63) == 0) redA[tid >> 6] = pa;
      __syncthreads();                                // S3: ua + redA
      float sigma2 = redA[0] + redA[1] + redA[2] + redA[3]
                   + redA[4] + redA[5] + redA[6] + redA[7];
      float v0 = ca[k + 1];
      if (sigma2 < 1e-30f){                           // uniform branch
        if (tid == 0) ee[k] = v0;
        continue;                                     // H = I
      }
      float sig = sqrtf(sigma2);
      float alpha = (v0 >= 0.f) ? -sig : sig;
      float u0 = v0 - alpha;
      float beta = 2.0f / (sigma2 - v0 * v0 + u0 * u0);
      if (tid == 0) ee[k] = alpha;
      if (tid == k + 1) ua[tid] = u0;
      __syncthreads();                                // S4: u final

      {
        float a0 = 0.f, a1 = 0.f, a2 = 0.f, a3 = 0.f;
        #pragma unroll
        for (int rr = 0; rr < 128; rr += 4){
          float4 u4 = *(const float4*)&ua[rowbase + rr];
          a0 = fmaf(Mreg[rr + 0], u4.x, a0);
          a1 = fmaf(Mreg[rr + 1], u4.y, a1);
          a2 = fmaf(Mreg[rr + 2], u4.z, a2);
          a3 = fmaf(Mreg[rr + 3], u4.w, a3);
        }
        ph[tid] = (a0 + a1) + (a2 + a3);
      }
      __syncthreads();                                // S5: ph
      float p = ph[c] + ph[c + 256];                  // (A u)_c
      float up = (tid < 256) ? ua[tid] * p : 0.f;
      float pb = wave_sum(up);
      if ((tid & 63) == 0) redB[tid >> 6] = pb;
      __syncthreads();                                // S6: redB
      float s = redB[0] + redB[1] + redB[2] + redB[3]
              + redB[4] + redB[5] + redB[6] + redB[7];
      if (tid < 256) wa[tid] = (tid > k) ? (beta * p - 0.5f * beta * beta * s * ua[tid]) : 0.f;
      __syncthreads();                                // S7: wa
      {
        float ucv = ua[c], wcv = wa[c];
        #pragma unroll
        for (int rr = 0; rr < 128; rr += 4){
          float4 u4 = *(const float4*)&ua[rowbase + rr];
          float4 w4 = *(const float4*)&wa[rowbase + rr];
          Mreg[rr + 0] = fmaf(-w4.x, ucv, fmaf(-u4.x, wcv, Mreg[rr + 0]));
          Mreg[rr + 1] = fmaf(-w4.y, ucv, fmaf(-u4.y, wcv, Mreg[rr + 1]));
          Mreg[rr + 2] = fmaf(-w4.z, ucv, fmaf(-u4.z, wcv, Mreg[rr + 2]));
          Mreg[rr + 3] = fmaf(-w4.w, ucv, fmaf(-u4.w, wcv, Mreg[rr + 3]));
        }
      }
    }

    // tail: dd[254], dd[255], ee[254]
    __syncthreads();
    if (c == 254){
      #pragma unroll
      for (int rr = 0; rr < 128; ++rr) ca[rowbase + rr] = Mreg[rr];
    }
    __syncthreads();
    if (tid == 0){ dd[254] = ca[254]; ee[254] = ca[255]; }
    __syncthreads();
    if (c == 255){
      #pragma unroll
      for (int rr = 0; rr < 128; ++rr) ca[rowbase + rr] = Mreg[rr];
    }
    __syncthreads();
    if (tid == 0){ dd[255] = ca[255]; ee[255] = 0.f; }
    __syncthreads();

    // ---- folded Sturm bisection (512 threads, h-duplicated; h==0 writes) ----
    float dvv = dd[c];
    float evv = ee[c];
    if (h == 0){ ua[c] = evv * evv; ph[c] = fabsf(evv); }
    __syncthreads();
    float rad = ph[c] + ((c > 0) ? ph[c - 1] : 0.f);
    float vmin = dvv - rad, vmax = dvv + rad;
    vmin = fminf(vmin, __shfl_xor(vmin, 32)); vmin = fminf(vmin, __shfl_xor(vmin, 16));
    vmin = fminf(vmin, __shfl_xor(vmin, 8));  vmin = fminf(vmin, __shfl_xor(vmin, 4));
    vmin = fminf(vmin, __shfl_xor(vmin, 2));  vmin = fminf(vmin, __shfl_xor(vmin, 1));
    vmax = fmaxf(vmax, __shfl_xor(vmax, 32)); vmax = fmaxf(vmax, __shfl_xor(vmax, 16));
    vmax = fmaxf(vmax, __shfl_xor(vmax, 8));  vmax = fmaxf(vmax, __shfl_xor(vmax, 4));
    vmax = fmaxf(vmax, __shfl_xor(vmax, 2));  vmax = fmaxf(vmax, __shfl_xor(vmax, 1));
    if (lane == 0){ redA[w] = vmin; redB[w] = vmax; }
    __syncthreads();
    float glo = fminf(fminf(fminf(redA[0], redA[1]), fminf(redA[2], redA[3])),
                      fminf(fminf(redA[4], redA[5]), fminf(redA[6], redA[7])));
    float ghi = fmaxf(fmaxf(fmaxf(redB[0], redB[1]), fmaxf(redB[2], redB[3])),
                      fmaxf(fmaxf(redB[4], redB[5]), fmaxf(redB[6], redB[7])));
    __syncthreads();

    float lo = glo, hi = ghi;
    for (int it = 0; it < 40; ++it){
      float mid = 0.5f * (lo + hi);
      float qv = dd[0] - mid;
      int cnt = (qv < 0.f) ? 1 : 0;
      #pragma unroll 8
      for (int i = 1; i < 256; ++i){
        float qr = __builtin_amdgcn_rcpf(qv);
        qv = (dd[i] - mid) - ua[i - 1] * qr;
        qv = (fabsf(qv) < 1e-25f) ? -1e-25f : qv;
        cnt += (qv < 0.f) ? 1 : 0;
      }
      if (cnt <= c) lo = mid; else hi = mid;
    }
    float lam = fmaxf(0.5f * (lo + hi), 1e-12f);
    float lp = (h == 0) ? lam : 0.f;
    lp = wave_sum(lp);
    if (lane == 0) redA[w] = lp;
    __syncthreads();
    float ssum = ((redA[0] + redA[1]) + (redA[2] + redA[3]))
               + ((redA[4] + redA[5]) + (redA[6] + redA[7]));
    if (h == 0)
      out[(size_t)SEQ_ * VOCAB_ + (size_t)t * 256 + c] = lam / ssum;
  } else {
    // ================= GEMM PATH =================
    short* A_lds = (short*)smem_raw;                 // [128 v][8 chunks of 8]
    short* B_lds = A_lds + 8192;                     // [256 n][8 chunks of 8]
    float* pl    = (float*)(B_lds + 16384);          // [8][64]
    const int g = blockIdx.x - 64;
    const int bx = g % 250, t = g / 250;
    const int lane = tid & 63, w = tid >> 6;
    const int wr = w >> 2, wc = w & 3;
    const int vbase = bx * 128;
    const short* E16 = (const short*)(ws + OFF_E16);
    const short* MN  = (const short*)(ws + OFF_MN16) + (size_t)t * 65536;

    f32x4 acc[4][4];
    #pragma unroll
    for (int i = 0; i < 4; ++i)
      #pragma unroll
      for (int j = 0; j < 4; ++j){ f32x4 z = {0.f, 0.f, 0.f, 0.f}; acc[i][j] = z; }

    const int gq = lane >> 4, r16 = lane & 15;
    const int sx = r16 & 7;                          // read-side XOR key
    for (int it = 0; it < 4; ++it){
      const int k0 = it * 64;
      __syncthreads();
      #pragma unroll
      for (int pa = 0; pa < 2; ++pa){
        int ch = pa * 512 + tid;
        int row = ch >> 3, c8 = ch & 7;
        int sc8 = c8 ^ (row & 7);                    // pre-swizzled source chunk
        uint4 v = *(const uint4*)(E16 + (size_t)(vbase + row) * 256 + k0 + sc8 * 8);
        *(uint4*)&A_lds[ch * 8] = v;                 // linear dest (conflict-free)
      }
      #pragma unroll
      for (int pb = 0; pb < 4; ++pb){
        int ch = pb * 512 + tid;
        int row = ch >> 3, c8 = ch & 7;
        int sc8 = c8 ^ (row & 7);
        uint4 v = *(const uint4*)(MN + (size_t)row * 256 + k0 + sc8 * 8);
        *(uint4*)&B_lds[ch * 8] = v;
      }
      __syncthreads();
      #pragma unroll
      for (int kk = 0; kk < 64; kk += 32){
        const int j0 = (kk >> 3) + gq;               // logical chunk index
        bf16x8 af[4], bf[4];
        #pragma unroll
        for (int fm = 0; fm < 4; ++fm)
          af[fm] = *(const bf16x8*)&A_lds[(wr * 64 + fm * 16 + r16) * 64 + (j0 ^ sx) * 8];
        #pragma unroll
        for (int fn = 0; fn < 4; ++fn)
          bf[fn] = *(const bf16x8*)&B_lds[(wc * 64 + fn * 16 + r16) * 64 + (j0 ^ sx) * 8];
        #pragma unroll
        for (int fm = 0; fm < 4; ++fm)
          #pragma unroll
          for (int fn = 0; fn < 4; ++fn)
            acc[fm][fn] = __builtin_amdgcn_mfma_f32_16x16x32_bf16(af[fm], bf[fn], acc[fm][fn], 0, 0, 0);
      }
    }

    // epilogue: square + reduce over n
    float ps[4][4];
    #pragma unroll
    for (int fm = 0; fm < 4; ++fm)
      #pragma unroll
      for (int i = 0; i < 4; ++i){
        float sv = 0.f;
        #pragma unroll
        for (int fn = 0; fn < 4; ++fn){ float v = acc[fm][fn][i]; sv += v * v; }
        sv += __shfl_xor(sv, 1); sv += __shfl_xor(sv, 2);
        sv += __shfl_xor(sv, 4); sv += __shfl_xor(sv, 8);
        ps[fm][i] = sv;
      }
    __syncthreads();
    if (r16 == 0){
      #pragma unroll
      for (int fm = 0; fm < 4; ++fm)
        #pragma unroll
        for (int i = 0; i < 4; ++i)
          pl[w * 64 + fm * 16 + gq * 4 + i] = ps[fm][i];
    }
    __syncthreads();
    if (tid < 128){
      int rr = tid;
      int wrr = rr >> 6, lr = rr & 63;
      float sum = pl[(wrr * 4 + 0) * 64 + lr] + pl[(wrr * 4 + 1) * 64 + lr]
                + pl[(wrr * 4 + 2) * 64 + lr] + pl[(wrr * 4 + 3) * 64 + lr];
      out[(size_t)t * VOCAB_ + vbase + rr] = sum * (1.0f / 256.0f);
    }
  }
}

// ---------------- host ----------------
extern "C" void kernel_launch(void* const* d_in, const int* in_sizes, int n_in,
                              void* d_out, int out_size, void* d_ws, size_t ws_size,
                              hipStream_t stream){
  const int*   tokens = (const int*)d_in[0];
  const float* E      = (const float*)d_in[1];
  const float* W      = (const float*)d_in[2];
  const float* mdbp   = (const float*)d_in[3];
  const float* nsp    = (const float*)d_in[4];
  float* out = (float*)d_out;
  float* ws  = (float*)d_ws;
  if (ws_size < WS_FLOATS * sizeof(float)) return;   // insufficient scratch -> clean fail

  k0_init<<<dim3(32000), dim3(256), 0, stream>>>(E, ws);
  k_wbar<<<dim3(256), dim3(256), 0, stream>>>(W, ws);
  k_xm<<<dim3(1), dim3(1024), 0, stream>>>(tokens, E, mdbp, nsp, ws);
  k_measall<<<dim3(256), dim3(256), 0, stream>>>(W, ws);
  {
    void* args[1];
    args[0] = (void*)&ws;
    hipLaunchCooperativeKernel((const void*)k_stats, dim3(64), dim3(1024), args, 0, stream);
  }
  k_rho<<<dim3(64, 8), dim3(256), 0, stream>>>(ws);
  k_trigemm<<<dim3(64 + 250 * 64), dim3(512), 0, stream>>>(ws, out);
}

// Round 11
// 3069.614 us; speedup vs baseline: 1.2786x; 1.0113x over previous
//
#include <hip/hip_runtime.h>
#include <hip/hip_bf16.h>
#include <cstdint>
#include <cstddef>

// ---------------- ws layout (float offsets) ----------------
constexpr size_t OFF_MEM    = 0;          // 65536   (unused; layout kept)
constexpr size_t OFF_XM     = 65536;      // 16384   xm[d][t] transposed (d*64+t)
constexpr size_t OFF_MU     = 82176;      // 16384   mu[t][d]
constexpr size_t OFF_SABS   = 98560;      // 64*4    per-step surprise sums (3 frames)
constexpr size_t OFF_BAR    = 98816;      // 1       grid-barrier epoch counter (zeroed by k0)
constexpr size_t ZERO_END   = 98880;
constexpr size_t OFF_WBAR   = 98880;      // 65536   Wbar = mean_n W  [d][e]
constexpr size_t OFF_MEANS  = 164416;     // (unused; layout kept)
constexpr size_t OFF_VARS   = 361024;     // (unused; layout kept)
constexpr size_t OFF_DT     = 557632;     // 64*256  tridiagonal diag
constexpr size_t OFF_ET     = 574016;     // 64*256  tridiagonal offdiag
constexpr size_t OFF_RHO    = 590400;     // 64*65536: meas[n][t][e] first, then rho[t] (aliased)
constexpr size_t OFF_MN16   = 4784704;    // bf16 mn [64][256][256] = 2097152 floats
constexpr size_t OFF_E16    = 6881856;    // bf16 E  [32000][256]  = 4096000 floats
constexpr size_t WS_FLOATS  = 10977856;   // ~41.9 MiB

#define SEQ_ 64
#define VOCAB_ 32000

typedef __attribute__((ext_vector_type(8))) short bf16x8;
typedef __attribute__((ext_vector_type(4))) float f32x4;

// ---------------- reduction helpers ----------------
__device__ __forceinline__ float wave_sum(float v){
  v += __shfl_xor(v, 32); v += __shfl_xor(v, 16); v += __shfl_xor(v, 8);
  v += __shfl_xor(v, 4);  v += __shfl_xor(v, 2);  v += __shfl_xor(v, 1);
  return v;
}
__device__ __forceinline__ float block_sum(float v, float* red){
  int tid = threadIdx.x;
  v = wave_sum(v);
  if ((tid & 63) == 0) red[tid >> 6] = v;
  __syncthreads();
  float r = red[0] + red[1] + red[2] + red[3];
  __syncthreads();
  return r;
}
__device__ __forceinline__ float block_min(float v, float* red){
  int tid = threadIdx.x;
  v = fminf(v, __shfl_xor(v, 32)); v = fminf(v, __shfl_xor(v, 16));
  v = fminf(v, __shfl_xor(v, 8));  v = fminf(v, __shfl_xor(v, 4));
  v = fminf(v, __shfl_xor(v, 2));  v = fminf(v, __shfl_xor(v, 1));
  if ((tid & 63) == 0) red[tid >> 6] = v;
  __syncthreads();
  float r = fminf(fminf(red[0], red[1]), fminf(red[2], red[3]));
  __syncthreads();
  return r;
}
__device__ __forceinline__ float block_max(float v, float* red){
  int tid = threadIdx.x;
  v = fmaxf(v, __shfl_xor(v, 32)); v = fmaxf(v, __shfl_xor(v, 16));
  v = fmaxf(v, __shfl_xor(v, 8));  v = fmaxf(v, __shfl_xor(v, 4));
  v = fmaxf(v, __shfl_xor(v, 2));  v = fmaxf(v, __shfl_xor(v, 1));
  if ((tid & 63) == 0) red[tid >> 6] = v;
  __syncthreads();
  float r = fmaxf(fmaxf(red[0], red[1]), fmaxf(red[2], red[3]));
  __syncthreads();
  return r;
}

// ---------------- K0: zero state + E -> bf16 ----------------
__global__ __launch_bounds__(256) void k0_init(const float* __restrict__ E, float* __restrict__ ws){
  size_t i = (size_t)blockIdx.x * 256 + threadIdx.x;   // exactly 8,192,000 threads
  if (i < ZERO_END) ws[i] = 0.f;
  __hip_bfloat16* e16 = (__hip_bfloat16*)(ws + OFF_E16);
  e16[i] = __float2bfloat16(E[i]);
}

// ---------------- K_wbar: Wbar[d][e] = mean_n W[n][d][e] ----------------
__global__ __launch_bounds__(256) void k_wbar(const float* __restrict__ W, float* __restrict__ ws){
  size_t i = (size_t)blockIdx.x * 256 + threadIdx.x;   // 65536 threads
  float s = 0.f;
  #pragma unroll 4
  for (int n = 0; n < 256; ++n)
    s += W[(size_t)n * 65536 + i];
  ws[OFF_WBAR + i] = s * (1.0f / 256.0f);
}

// ---------------- K_xm: sequential scalar recurrence (1 block, 1024 threads) ----------------
// Wbar quarter-column held in 64 REGISTERS per thread (t-invariant; loaded once)
// -> per-step matvec is pure LDS+FMA, no L2 loads in the serial chain.
__global__ __launch_bounds__(1024, 1) void k_xm(const int* __restrict__ tokens,
    const float* __restrict__ E, const float* __restrict__ mdbp,
    const float* __restrict__ nsp, float* __restrict__ ws){
  __shared__ float xm_s[256];
  __shared__ __align__(16) float part[4][256];
  __shared__ float redA[16], redB[16], redC[16];
  const int tid = threadIdx.x;
  const int e = tid & 255, q = tid >> 8;
  const int lane = tid & 63, w = tid >> 6;
  const float sens = fabsf(nsp[0]);
  const float mdb  = mdbp[0];
  const float* Wb = ws + OFF_WBAR;
  float mm = 0.f;                                    // valid on tid<256; 0 elsewhere

  // preload my Wbar quarter-column: wreg[dd] = Wbar[q*64+dd][e]
  float wreg[64];
  {
    const float* Wq = Wb + (size_t)(q * 64) * 256 + e;
    #pragma unroll
    for (int dd = 0; dd < 64; ++dd)
      wreg[dd] = Wq[(size_t)dd * 256];
  }

  for (int t = 0; t < SEQ_; ++t){
    int tok = tokens[t];
    float xv = (tid < 256) ? E[(size_t)tok * 256 + e] : 0.f;
    float a = wave_sum(xv * mm);
    float b = wave_sum(xv * xv);
    float c = wave_sum(mm * mm);
    if (lane == 0){ redA[w] = a; redB[w] = b; redC[w] = c; }
    __syncthreads();                                 // S1: partials ready
    float sdot = (redA[0] + redA[1]) + (redA[2] + redA[3]);
    float sx2  = (redB[0] + redB[1]) + (redB[2] + redB[3]);
    float sm2  = (redC[0] + redC[1]) + (redC[2] + redC[3]);
    float mem_norm = sqrtf(sm2) + 1e-10f;
    float x_norm   = sqrtf(sx2) + 1e-10f;
    float novelty = (mem_norm > 1e-8f) ? (1.0f - sdot / (x_norm * mem_norm)) : 1.0f;
    float z = mdb - sens * novelty;
    float decay = 1.0f / (1.0f + expf(-z));
    if (tid < 256){
      float xmv = xv + decay * mm;
      xm_s[e] = xmv;
      ws[OFF_XM + (size_t)e * 64 + t] = xmv;         // transposed for k_measall
    }
    __syncthreads();                                 // S2: xm_s ready

    float p = 0.f;
    #pragma unroll
    for (int dd = 0; dd < 64; ++dd)
      p = fmaf(xm_s[q * 64 + dd], wreg[dd], p);
    part[q][e] = p;
    __syncthreads();                                 // S3: partials ready
    if (tid < 256){
      float acc = (part[0][e] + part[1][e]) + (part[2][e] + part[3][e]);
      ws[OFF_MU + (size_t)t * 256 + e] = acc;
      mm = decay * mm + (1.0f - decay) * acc;
    }
    __syncthreads();                                 // S4: reuse guard
  }
}

// ---------------- K_measall: meas[n][t][e] = sum_d xm[t][d] W[n][d][e] ----------------
__global__ __launch_bounds__(256) void k_measall(const float* __restrict__ W, float* __restrict__ ws){
  __shared__ __align__(16) float xm_s[16384];        // [d][t] (d*64+t)
  const int tid = threadIdx.x, n = blockIdx.x;
  for (int i = tid; i < 16384; i += 256) xm_s[i] = ws[OFF_XM + i];
  __syncthreads();

  float acc[64];
  #pragma unroll
  for (int t = 0; t < 64; ++t) acc[t] = 0.f;

  const float* Wn = W + (size_t)n * 65536 + tid;
  for (int d = 0; d < 256; ++d){
    float wv = Wn[(size_t)d * 256];
    const float* xr = &xm_s[d * 64];
    #pragma unroll
    for (int q = 0; q < 16; ++q){
      float4 x4 = *(const float4*)&xr[q * 4];
      acc[q * 4 + 0] = fmaf(x4.x, wv, acc[q * 4 + 0]);
      acc[q * 4 + 1] = fmaf(x4.y, wv, acc[q * 4 + 1]);
      acc[q * 4 + 2] = fmaf(x4.z, wv, acc[q * 4 + 2]);
      acc[q * 4 + 3] = fmaf(x4.w, wv, acc[q * 4 + 3]);
    }
  }
  #pragma unroll
  for (int t = 0; t < 64; ++t)
    ws[OFF_RHO + (size_t)n * 16384 + (size_t)t * 256 + tid] = acc[t];
}

// ---------------- K_stats: sequential know/means/vars recurrence ----------------
__global__ __launch_bounds__(1024, 1) void k_stats(float* __restrict__ ws){
  __shared__ float redA[16], redB[16], redC[16];
  const int tid = threadIdx.x;
  const int e = tid & 255, q = tid >> 8;
  const int lane = tid & 63, w = tid >> 6;
  const int n = blockIdx.x * 4 + q;
  unsigned* bar = (unsigned*)(ws + OFF_BAR);
  __hip_bfloat16* mn16 = (__hip_bfloat16*)(ws + OFF_MN16);
  const size_t ne = (size_t)n * 256 + e;
  const float TH = 1.5f * 65536.0f;
  const float c5 = 0.59049f;                         // 0.9^5

  float mean0 = 0.f, mean1 = 0.f, mean2 = 0.f;
  float var0 = 0.f, var1 = 0.f, var2 = 0.f;

  for (int t = 0; t < SEQ_; ++t){
    float me = ws[OFF_RHO + (size_t)n * 16384 + (size_t)t * 256 + e];
    bool know = false;
    if (t > 0){
      float v0 = fabsf(me - mean0) / sqrtf(var0 + 1e-8f);
      float v1 = fabsf(me - mean1) / sqrtf(var1 + 1e-8f);
      float v2 = fabsf(me - mean2) / sqrtf(var2 + 1e-8f);
      float a = wave_sum(v0), b = wave_sum(v1), c = wave_sum(v2);
      if (lane == 0){ redA[w] = a; redB[w] = b; redC[w] = c; }
      __syncthreads();                               // S1: partials ready
      if (tid == 0){
        float sA = 0.f, sB = 0.f, sC = 0.f;
        #pragma unroll
        for (int i = 0; i < 16; ++i){ sA += redA[i]; sB += redB[i]; sC += redC[i]; }
        atomicAdd(&ws[OFF_SABS + (size_t)t * 4 + 0], sA);
        atomicAdd(&ws[OFF_SABS + (size_t)t * 4 + 1], sB);
        atomicAdd(&ws[OFF_SABS + (size_t)t * 4 + 2], sC);
        __hip_atomic_fetch_add(bar, 1u, __ATOMIC_ACQ_REL, __HIP_MEMORY_SCOPE_AGENT);
        unsigned tgt = 64u * (unsigned)t;
        while (__hip_atomic_load(bar, __ATOMIC_ACQUIRE, __HIP_MEMORY_SCOPE_AGENT) < tgt)
          __builtin_amdgcn_s_sleep(2);
      }
      __syncthreads();                               // S2: sabs complete everywhere
      float s0 = __hip_atomic_load(&ws[OFF_SABS + (size_t)t * 4 + 0], __ATOMIC_RELAXED, __HIP_MEMORY_SCOPE_AGENT);
      float s1 = __hip_atomic_load(&ws[OFF_SABS + (size_t)t * 4 + 1], __ATOMIC_RELAXED, __HIP_MEMORY_SCOPE_AGENT);
      float s2 = __hip_atomic_load(&ws[OFF_SABS + (size_t)t * 4 + 2], __ATOMIC_RELAXED, __HIP_MEMORY_SCOPE_AGENT);
      know = (s0 < TH) || (s1 < TH) || (s2 < TH);
    }
    float mu = ws[OFF_MU + (size_t)t * 256 + e];
    float eq = c5 * me + (1.0f - c5) * mu;
    float eff = know ? me : eq;

    if (t == 0){
      mean0 = eff; mean1 = eff; mean2 = eff;
      var0 = 0.1f; var1 = 0.1f; var2 = 0.1f;
    } else {
      float um, uv;
      um = 0.3f * mean0 + 0.7f * eff;
      uv = 0.3f * var0 + 0.7f * (eff - mean0) * (eff - um);
      mean0 = um; var0 = fmaxf(uv, 1e-8f);
      um = 0.7f * mean1 + 0.3f * eff;
      uv = 0.7f * var1 + 0.3f * (eff - mean1) * (eff - um);
      mean1 = um; var1 = fmaxf(uv, 1e-8f);
      um = 0.9f * mean2 + 0.1f * eff;
      uv = 0.9f * var2 + 0.1f * (eff - mean2) * (eff - um);
      mean2 = um; var2 = fmaxf(uv, 1e-8f);
    }

    float nv = wave_sum(eff * eff);
    if (lane == 0) redA[w] = nv;
    __syncthreads();                                 // S3: quarter partials
    float nr2 = (redA[4 * q + 0] + redA[4 * q + 1]) + (redA[4 * q + 2] + redA[4 * q + 3]);
    float rn = sqrtf(nr2) + 1e-10f;
    mn16[(size_t)t * 65536 + ne] = __float2bfloat16(eff / rn);
    __syncthreads();                                 // S4: red reuse guard
  }
}

// ---------------- K_rho: rho[t] = mn^T mn / NB (fp32 accum from bf16) ----------------
__global__ __launch_bounds__(256) void k_rho(float* __restrict__ ws){
  const int t = blockIdx.x, rb = blockIdx.y, tid = threadIdx.x;
  __shared__ __align__(16) float tile[32][256];
  const unsigned short* mn16 = (const unsigned short*)(ws + OFF_MN16);
  float acc[32];
  #pragma unroll
  for (int i = 0; i < 32; ++i) acc[i] = 0.f;
  for (int c = 0; c < 8; ++c){
    __syncthreads();
    // vectorized: 8192 bf16 per chunk = 1024 uint4; 4 per thread
    #pragma unroll
    for (int v = 0; v < 4; ++v){
      int idx = v * 256 + tid;
      int row = idx >> 5, c16 = idx & 31;
      uint4 u4 = *(const uint4*)(mn16 + (size_t)t * 65536 + (size_t)(c * 32 + row) * 256 + c16 * 8);
      float* dst = &tile[row][c16 * 8];
      unsigned uu[4] = {u4.x, u4.y, u4.z, u4.w};
      #pragma unroll
      for (int j = 0; j < 4; ++j){
        dst[j * 2 + 0] = __uint_as_float(uu[j] << 16);
        dst[j * 2 + 1] = __uint_as_float(uu[j] & 0xffff0000u);
      }
    }
    __syncthreads();
    for (int nl = 0; nl < 32; ++nl){
      float ev = tile[nl][tid];
      #pragma unroll
      for (int q = 0; q < 8; ++q){
        float4 dv = *(const float4*)&tile[nl][rb * 32 + q * 4];
        acc[q * 4 + 0] = fmaf(dv.x, ev, acc[q * 4 + 0]);
        acc[q * 4 + 1] = fmaf(dv.y, ev, acc[q * 4 + 1]);
        acc[q * 4 + 2] = fmaf(dv.z, ev, acc[q * 4 + 2]);
        acc[q * 4 + 3] = fmaf(dv.w, ev, acc[q * 4 + 3]);
      }
    }
  }
  #pragma unroll
  for (int i = 0; i < 32; ++i)
    ws[OFF_RHO + (size_t)t * 65536 + (size_t)(rb * 32 + i) * 256 + tid] = acc[i] * (1.0f / 256.0f);
}

// ---------------- K_trigemm: fused k_tri (blocks 0..63) + k_gemm (blocks 64..16063) ----------------
// EXACT round-9 body (measured 1910us fused): tri path writes dT/eT to global,
// NO bisect tail (the round-10 fold perturbed the k-loop codegen, +407us).
__global__ __launch_bounds__(512, 2) void k_trigemm(float* __restrict__ ws, float* __restrict__ out){
  __shared__ __align__(16) char smem_raw[51200];
  const int tid = threadIdx.x;

  if (blockIdx.x < 64){
    // ================= TRI PATH =================
    float* ca   = (float*)smem_raw;          // 256
    float* ua   = ca + 256;                  // 256
    float* wa   = ua + 256;                  // 256
    float* ph   = wa + 256;                  // 512
    float* redA = ph + 512;                  // 8
    float* redB = redA + 8;                  // 8
    const int t = blockIdx.x;
    const int c = tid & 255, h = tid >> 8;
    const float* rho = ws + OFF_RHO + (size_t)t * 65536;
    float* dT = ws + OFF_DT + (size_t)t * 256;
    float* eT = ws + OFF_ET + (size_t)t * 256;

    float Mreg[128];
    {
      const float* Mc = rho + (size_t)(h * 128) * 256 + c;
      #pragma unroll
      for (int rr = 0; rr < 128; ++rr)
        Mreg[rr] = Mc[(size_t)rr * 256];
    }
    const int rowbase = h * 128;

    for (int k = 0; k < 254; ++k){
      __syncthreads();                                // S1: prev update done
      if (c == k){
        #pragma unroll
        for (int rr = 0; rr < 128; ++rr) ca[rowbase + rr] = Mreg[rr];
      }
      __syncthreads();                                // S2: ca visible
      float uval = 0.f;
      if (tid < 256){
        float raw = ca[tid];
        uval = (tid > k) ? raw : 0.f;
        ua[tid] = uval;
        if (tid == 0) dT[k] = ca[k];
      }
      float pa = wave_sum(uval * uval);
      if ((tid & 63) == 0) redA[tid >> 6] = pa;
      __syncthreads();                                // S3: ua + redA
      float sigma2 = redA[0] + redA[1] + redA[2] + redA[3]
                   + redA[4] + redA[5] + redA[6] + redA[7];
      float v0 = ca[k + 1];
      if (sigma2 < 1e-30f){                           // uniform branch
        if (tid == 0) eT[k] = v0;
        continue;                                     // H = I
      }
      float sig = sqrtf(sigma2);
      float alpha = (v0 >= 0.f) ? -sig : sig;
      float u0 = v0 - alpha;
      float beta = 2.0f / (sigma2 - v0 * v0 + u0 * u0);
      if (tid == 0) eT[k] = alpha;
      if (tid == k + 1) ua[tid] = u0;
      __syncthreads();                                // S4: u final

      {
        float a0 = 0.f, a1 = 0.f, a2 = 0.f, a3 = 0.f;
        #pragma unroll
        for (int rr = 0; rr < 128; rr += 4){
          float4 u4 = *(const float4*)&ua[rowbase + rr];
          a0 = fmaf(Mreg[rr + 0], u4.x, a0);
          a1 = fmaf(Mreg[rr + 1], u4.y, a1);
          a2 = fmaf(Mreg[rr + 2], u4.z, a2);
          a3 = fmaf(Mreg[rr + 3], u4.w, a3);
        }
        ph[tid] = (a0 + a1) + (a2 + a3);
      }
      __syncthreads();                                // S5: ph
      float p = ph[c] + ph[c + 256];                  // (A u)_c
      float up = (tid < 256) ? ua[tid] * p : 0.f;
      float pb = wave_sum(up);
      if ((tid & 63) == 0) redB[tid >> 6] = pb;
      __syncthreads();                                // S6: redB
      float s = redB[0] + redB[1] + redB[2] + redB[3]
              + redB[4] + redB[5] + redB[6] + redB[7];
      if (tid < 256) wa[tid] = (tid > k) ? (beta * p - 0.5f * beta * beta * s * ua[tid]) : 0.f;
      __syncthreads();                                // S7: wa
      {
        float ucv = ua[c], wcv = wa[c];
        #pragma unroll
        for (int rr = 0; rr < 128; rr += 4){
          float4 u4 = *(const float4*)&ua[rowbase + rr];
          float4 w4 = *(const float4*)&wa[rowbase + rr];
          Mreg[rr + 0] = fmaf(-w4.x, ucv, fmaf(-u4.x, wcv, Mreg[rr + 0]));
          Mreg[rr + 1] = fmaf(-w4.y, ucv, fmaf(-u4.y, wcv, Mreg[rr + 1]));
          Mreg[rr + 2] = fmaf(-w4.z, ucv, fmaf(-u4.z, wcv, Mreg[rr + 2]));
          Mreg[rr + 3] = fmaf(-w4.w, ucv, fmaf(-u4.w, wcv, Mreg[rr + 3]));
        }
      }
    }

    // tail: dT[254], dT[255], eT[254]
    __syncthreads();
    if (c == 254){
      #pragma unroll
      for (int rr = 0; rr < 128; ++rr) ca[rowbase + rr] = Mreg[rr];
    }
    __syncthreads();
    if (tid == 0){ dT[254] = ca[254]; eT[254] = ca[255]; }
    __syncthreads();
    if (c == 255){
      #pragma unroll
      for (int rr = 0; rr < 128; ++rr) ca[rowbase + rr] = Mreg[rr];
    }
    __syncthreads();
    if (tid == 0){ dT[255] = ca[255]; eT[255] = 0.f; }
  } else {
    // ================= GEMM PATH =================
    short* A_lds = (short*)smem_raw;                 // [128 v][8 chunks of 8]
    short* B_lds = A_lds + 8192;                     // [256 n][8 chunks of 8]
    float* pl    = (float*)(B_lds + 16384);          // [8][64]
    const int g = blockIdx.x - 64;
    const int bx = g % 250, t = g / 250;
    const int lane = tid & 63, w = tid >> 6;
    const int wr = w >> 2, wc = w & 3;
    const int vbase = bx * 128;
    const short* E16 = (const short*)(ws + OFF_E16);
    const short* MN  = (const short*)(ws + OFF_MN16) + (size_t)t * 65536;

    f32x4 acc[4][4];
    #pragma unroll
    for (int i = 0; i < 4; ++i)
      #pragma unroll
      for (int j = 0; j < 4; ++j){ f32x4 z = {0.f, 0.f, 0.f, 0.f}; acc[i][j] = z; }

    const int gq = lane >> 4, r16 = lane & 15;
    const int sx = r16 & 7;                          // read-side XOR key
    for (int it = 0; it < 4; ++it){
      const int k0 = it * 64;
      __syncthreads();
      #pragma unroll
      for (int pa = 0; pa < 2; ++pa){
        int ch = pa * 512 + tid;
        int row = ch >> 3, c8 = ch & 7;
        int sc8 = c8 ^ (row & 7);                    // pre-swizzled source chunk
        uint4 v = *(const uint4*)(E16 + (size_t)(vbase + row) * 256 + k0 + sc8 * 8);
        *(uint4*)&A_lds[ch * 8] = v;                 // linear dest (conflict-free)
      }
      #pragma unroll
      for (int pb = 0; pb < 4; ++pb){
        int ch = pb * 512 + tid;
        int row = ch >> 3, c8 = ch & 7;
        int sc8 = c8 ^ (row & 7);
        uint4 v = *(const uint4*)(MN + (size_t)row * 256 + k0 + sc8 * 8);
        *(uint4*)&B_lds[ch * 8] = v;
      }
      __syncthreads();
      #pragma unroll
      for (int kk = 0; kk < 64; kk += 32){
        const int j0 = (kk >> 3) + gq;               // logical chunk index
        bf16x8 af[4], bf[4];
        #pragma unroll
        for (int fm = 0; fm < 4; ++fm)
          af[fm] = *(const bf16x8*)&A_lds[(wr * 64 + fm * 16 + r16) * 64 + (j0 ^ sx) * 8];
        #pragma unroll
        for (int fn = 0; fn < 4; ++fn)
          bf[fn] = *(const bf16x8*)&B_lds[(wc * 64 + fn * 16 + r16) * 64 + (j0 ^ sx) * 8];
        #pragma unroll
        for (int fm = 0; fm < 4; ++fm)
          #pragma unroll
          for (int fn = 0; fn < 4; ++fn)
            acc[fm][fn] = __builtin_amdgcn_mfma_f32_16x16x32_bf16(af[fm], bf[fn], acc[fm][fn], 0, 0, 0);
      }
    }

    // epilogue: square + reduce over n
    float ps[4][4];
    #pragma unroll
    for (int fm = 0; fm < 4; ++fm)
      #pragma unroll
      for (int i = 0; i < 4; ++i){
        float sv = 0.f;
        #pragma unroll
        for (int fn = 0; fn < 4; ++fn){ float v = acc[fm][fn][i]; sv += v * v; }
        sv += __shfl_xor(sv, 1); sv += __shfl_xor(sv, 2);
        sv += __shfl_xor(sv, 4); sv += __shfl_xor(sv, 8);
        ps[fm][i] = sv;
      }
    __syncthreads();
    if (r16 == 0){
      #pragma unroll
      for (int fm = 0; fm < 4; ++fm)
        #pragma unroll
        for (int i = 0; i < 4; ++i)
          pl[w * 64 + fm * 16 + gq * 4 + i] = ps[fm][i];
    }
    __syncthreads();
    if (tid < 128){
      int rr = tid;
      int wrr = rr >> 6, lr = rr & 63;
      float sum = pl[(wrr * 4 + 0) * 64 + lr] + pl[(wrr * 4 + 1) * 64 + lr]
                + pl[(wrr * 4 + 2) * 64 + lr] + pl[(wrr * 4 + 3) * 64 + lr];
      out[(size_t)t * VOCAB_ + vbase + rr] = sum * (1.0f / 256.0f);
    }
  }
}

// ---------------- K_bisect: Sturm bisection, one eigenvalue per thread ----------------
__global__ __launch_bounds__(256) void k_bisect(const float* __restrict__ ws, float* __restrict__ out){
  __shared__ float d_s[256];
  __shared__ float e2_s[256];
  __shared__ float ea_s[256];
  __shared__ float red[4];
  const int t = blockIdx.x, tid = threadIdx.x;
  d_s[tid] = ws[OFF_DT + (size_t)t * 256 + tid];
  float evv = (tid < 255) ? ws[OFF_ET + (size_t)t * 256 + tid] : 0.f;
  e2_s[tid] = evv * evv;
  ea_s[tid] = fabsf(evv);
  __syncthreads();
  float rad = ea_s[tid] + ((tid > 0) ? ea_s[tid - 1] : 0.f);
  float glo = block_min(d_s[tid] - rad, red);
  float ghi = block_max(d_s[tid] + rad, red);

  float l = glo, h = ghi;
  for (int it = 0; it < 40; ++it){
    float mid = 0.5f * (l + h);
    float q = d_s[0] - mid;
    int cnt = (q < 0.f) ? 1 : 0;
    #pragma unroll 8
    for (int i = 1; i < 256; ++i){
      float qr = __builtin_amdgcn_rcpf(q);
      q = (d_s[i] - mid) - e2_s[i - 1] * qr;
      q = (fabsf(q) < 1e-25f) ? -1e-25f : q;
      cnt += (q < 0.f) ? 1 : 0;
    }
    if (cnt <= tid) l = mid; else h = mid;
  }
  float lam = fmaxf(0.5f * (l + h), 1e-12f);
  float ssum = block_sum(lam, red);
  out[(size_t)SEQ_ * VOCAB_ + (size_t)t * 256 + tid] = lam / ssum;
}

// ---------------- host ----------------
extern "C" void kernel_launch(void* const* d_in, const int* in_sizes, int n_in,
                              void* d_out, int out_size, void* d_ws, size_t ws_size,
                              hipStream_t stream){
  const int*   tokens = (const int*)d_in[0];
  const float* E      = (const float*)d_in[1];
  const float* W      = (const float*)d_in[2];
  const float* mdbp   = (const float*)d_in[3];
  const float* nsp    = (const float*)d_in[4];
  float* out = (float*)d_out;
  float* ws  = (float*)d_ws;
  if (ws_size < WS_FLOATS * sizeof(float)) return;   // insufficient scratch -> clean fail

  k0_init<<<dim3(32000), dim3(256), 0, stream>>>(E, ws);
  k_wbar<<<dim3(256), dim3(256), 0, stream>>>(W, ws);
  k_xm<<<dim3(1), dim3(1024), 0, stream>>>(tokens, E, mdbp, nsp, ws);
  k_measall<<<dim3(256), dim3(256), 0, stream>>>(W, ws);
  {
    void* args[1];
    args[0] = (void*)&ws;
    hipLaunchCooperativeKernel((const void*)k_stats, dim3(64), dim3(1024), args, 0, stream);
  }
  k_rho<<<dim3(64, 8), dim3(256), 0, stream>>>(ws);
  k_trigemm<<<dim3(64 + 250 * 64), dim3(512), 0, stream>>>(ws, out);
  k_bisect<<<dim3(64), dim3(256), 0, stream>>>(ws, out);
}

// Round 12
// 2939.861 us; speedup vs baseline: 1.3351x; 1.0441x over previous
//
#include <hip/hip_runtime.h>
#include <hip/hip_bf16.h>
#include <cstdint>
#include <cstddef>

// ---------------- ws layout (float offsets) ----------------
constexpr size_t OFF_MEM    = 0;          // 65536   (unused; layout kept)
constexpr size_t OFF_XM     = 65536;      // 16384   xm[d][t] transposed (d*64+t)
constexpr size_t OFF_MU     = 82176;      // 16384   mu[t][d]
constexpr size_t OFF_SABS   = 98560;      // 64*4    (unused now; layout kept)
constexpr size_t OFF_BAR    = 98816;      // 1       grid-barrier epoch counter (zeroed by k0)
constexpr size_t ZERO_END   = 98880;
constexpr size_t OFF_WBAR   = 98880;      // 65536   Wbar = mean_n W  [d][e]
constexpr size_t OFF_MEANS  = 164416;     // reused: sabsP [t][f][block] = 64*3*64 floats
constexpr size_t OFF_VARS   = 361024;     // (unused; layout kept)
constexpr size_t OFF_DT     = 557632;     // 64*256  tridiagonal diag
constexpr size_t OFF_ET     = 574016;     // 64*256  tridiagonal offdiag
constexpr size_t OFF_RHO    = 590400;     // 64*65536: meas[n][t][e] first, then rho[t] (aliased)
constexpr size_t OFF_MN16   = 4784704;    // bf16 mn [64][256][256] = 2097152 floats
constexpr size_t OFF_E16    = 6881856;    // bf16 E  [32000][256]  = 4096000 floats
constexpr size_t WS_FLOATS  = 10977856;   // ~41.9 MiB

#define SEQ_ 64
#define VOCAB_ 32000

typedef __attribute__((ext_vector_type(8))) short bf16x8;
typedef __attribute__((ext_vector_type(4))) float f32x4;

// ---------------- reduction helpers ----------------
__device__ __forceinline__ float wave_sum(float v){
  v += __shfl_xor(v, 32); v += __shfl_xor(v, 16); v += __shfl_xor(v, 8);
  v += __shfl_xor(v, 4);  v += __shfl_xor(v, 2);  v += __shfl_xor(v, 1);
  return v;
}
__device__ __forceinline__ float block_sum(float v, float* red){
  int tid = threadIdx.x;
  v = wave_sum(v);
  if ((tid & 63) == 0) red[tid >> 6] = v;
  __syncthreads();
  float r = red[0] + red[1] + red[2] + red[3];
  __syncthreads();
  return r;
}
__device__ __forceinline__ float block_min(float v, float* red){
  int tid = threadIdx.x;
  v = fminf(v, __shfl_xor(v, 32)); v = fminf(v, __shfl_xor(v, 16));
  v = fminf(v, __shfl_xor(v, 8));  v = fminf(v, __shfl_xor(v, 4));
  v = fminf(v, __shfl_xor(v, 2));  v = fminf(v, __shfl_xor(v, 1));
  if ((tid & 63) == 0) red[tid >> 6] = v;
  __syncthreads();
  float r = fminf(fminf(red[0], red[1]), fminf(red[2], red[3]));
  __syncthreads();
  return r;
}
__device__ __forceinline__ float block_max(float v, float* red){
  int tid = threadIdx.x;
  v = fmaxf(v, __shfl_xor(v, 32)); v = fmaxf(v, __shfl_xor(v, 16));
  v = fmaxf(v, __shfl_xor(v, 8));  v = fmaxf(v, __shfl_xor(v, 4));
  v = fmaxf(v, __shfl_xor(v, 2));  v = fmaxf(v, __shfl_xor(v, 1));
  if ((tid & 63) == 0) red[tid >> 6] = v;
  __syncthreads();
  float r = fmaxf(fmaxf(red[0], red[1]), fmaxf(red[2], red[3]));
  __syncthreads();
  return r;
}

// ---------------- K0: zero state + E -> bf16 + Wbar (k_wbar merged) ----------------
__global__ __launch_bounds__(256) void k0_init(const float* __restrict__ E,
    const float* __restrict__ W, float* __restrict__ ws){
  size_t i = (size_t)blockIdx.x * 256 + threadIdx.x;   // exactly 8,192,000 threads
  if (i < ZERO_END) ws[i] = 0.f;
  __hip_bfloat16* e16 = (__hip_bfloat16*)(ws + OFF_E16);
  e16[i] = __float2bfloat16(E[i]);
  if (blockIdx.x < 256){                               // Wbar[d][e] = mean_n W[n][d][e]
    float s = 0.f;
    #pragma unroll 4
    for (int n = 0; n < 256; ++n)
      s += W[(size_t)n * 65536 + i];
    ws[OFF_WBAR + i] = s * (1.0f / 256.0f);
  }
}

// ---------------- K_xm: sequential scalar recurrence (1 block, 1024 threads) ----------------
// Wbar quarter-column in 64 registers; 3 barriers/step (S4 proven redundant:
// every cross-step LDS hazard is separated by S1..S3 of the next iteration).
__global__ __launch_bounds__(1024, 1) void k_xm(const int* __restrict__ tokens,
    const float* __restrict__ E, const float* __restrict__ mdbp,
    const float* __restrict__ nsp, float* __restrict__ ws){
  __shared__ float xm_s[256];
  __shared__ __align__(16) float part[4][256];
  __shared__ float redA[16], redB[16], redC[16];
  const int tid = threadIdx.x;
  const int e = tid & 255, q = tid >> 8;
  const int lane = tid & 63, w = tid >> 6;
  const float sens = fabsf(nsp[0]);
  const float mdb  = mdbp[0];
  const float* Wb = ws + OFF_WBAR;
  float mm = 0.f;                                    // valid on tid<256; 0 elsewhere

  // preload my Wbar quarter-column: wreg[dd] = Wbar[q*64+dd][e]
  float wreg[64];
  {
    const float* Wq = Wb + (size_t)(q * 64) * 256 + e;
    #pragma unroll
    for (int dd = 0; dd < 64; ++dd)
      wreg[dd] = Wq[(size_t)dd * 256];
  }

  for (int t = 0; t < SEQ_; ++t){
    int tok = tokens[t];
    float xv = (tid < 256) ? E[(size_t)tok * 256 + e] : 0.f;
    float a = wave_sum(xv * mm);
    float b = wave_sum(xv * xv);
    float c = wave_sum(mm * mm);
    if (lane == 0){ redA[w] = a; redB[w] = b; redC[w] = c; }
    __syncthreads();                                 // S1: partials ready
    float sdot = (redA[0] + redA[1]) + (redA[2] + redA[3]);
    float sx2  = (redB[0] + redB[1]) + (redB[2] + redB[3]);
    float sm2  = (redC[0] + redC[1]) + (redC[2] + redC[3]);
    float mem_norm = sqrtf(sm2) + 1e-10f;
    float x_norm   = sqrtf(sx2) + 1e-10f;
    float novelty = (mem_norm > 1e-8f) ? (1.0f - sdot / (x_norm * mem_norm)) : 1.0f;
    float z = mdb - sens * novelty;
    float decay = 1.0f / (1.0f + expf(-z));
    if (tid < 256){
      float xmv = xv + decay * mm;
      xm_s[e] = xmv;
      ws[OFF_XM + (size_t)e * 64 + t] = xmv;         // transposed for k_measall
    }
    __syncthreads();                                 // S2: xm_s ready

    float p = 0.f;
    #pragma unroll
    for (int dd = 0; dd < 64; ++dd)
      p = fmaf(xm_s[q * 64 + dd], wreg[dd], p);
    part[q][e] = p;
    __syncthreads();                                 // S3: partials ready
    if (tid < 256){
      float acc = (part[0][e] + part[1][e]) + (part[2][e] + part[3][e]);
      ws[OFF_MU + (size_t)t * 256 + e] = acc;
      mm = decay * mm + (1.0f - decay) * acc;
    }
    // no S4: next-iteration S1/S2 separate all reuse hazards
  }
}

// ---------------- K_measall: meas[n][t][e] = sum_d xm[t][d] W[n][d][e] ----------------
__global__ __launch_bounds__(256) void k_measall(const float* __restrict__ W, float* __restrict__ ws){
  __shared__ __align__(16) float xm_s[16384];        // [d][t] (d*64+t)
  const int tid = threadIdx.x, n = blockIdx.x;
  for (int i = tid; i < 16384; i += 256) xm_s[i] = ws[OFF_XM + i];
  __syncthreads();

  float acc[64];
  #pragma unroll
  for (int t = 0; t < 64; ++t) acc[t] = 0.f;

  const float* Wn = W + (size_t)n * 65536 + tid;
  for (int d = 0; d < 256; ++d){
    float wv = Wn[(size_t)d * 256];
    const float* xr = &xm_s[d * 64];
    #pragma unroll
    for (int q = 0; q < 16; ++q){
      float4 x4 = *(const float4*)&xr[q * 4];
      acc[q * 4 + 0] = fmaf(x4.x, wv, acc[q * 4 + 0]);
      acc[q * 4 + 1] = fmaf(x4.y, wv, acc[q * 4 + 1]);
      acc[q * 4 + 2] = fmaf(x4.z, wv, acc[q * 4 + 2]);
      acc[q * 4 + 3] = fmaf(x4.w, wv, acc[q * 4 + 3]);
    }
  }
  #pragma unroll
  for (int t = 0; t < 64; ++t)
    ws[OFF_RHO + (size_t)n * 16384 + (size_t)t * 256 + tid] = acc[t];
}

// ---------------- K_stats: sequential know/means/vars recurrence ----------------
// Cooperative, 64 blocks x 1024 threads. Cross-block sabs via per-block partial
// STORES (distinct lines, no atomic serialization) + per-wave redundant 64-lane
// reduction after the epoch barrier. Dedicated redD for the norm -> 3 barriers.
__global__ __launch_bounds__(1024, 1) void k_stats(float* __restrict__ ws){
  __shared__ float redA[16], redB[16], redC[16], redD[16];
  const int tid = threadIdx.x;
  const int e = tid & 255, q = tid >> 8;
  const int lane = tid & 63, w = tid >> 6;
  const int n = blockIdx.x * 4 + q;
  unsigned* bar = (unsigned*)(ws + OFF_BAR);
  float* sabsP = ws + OFF_MEANS;                     // [t][f][block] partials
  __hip_bfloat16* mn16 = (__hip_bfloat16*)(ws + OFF_MN16);
  const size_t ne = (size_t)n * 256 + e;
  const float TH = 1.5f * 65536.0f;
  const float c5 = 0.59049f;                         // 0.9^5

  float mean0 = 0.f, mean1 = 0.f, mean2 = 0.f;
  float var0 = 0.f, var1 = 0.f, var2 = 0.f;

  for (int t = 0; t < SEQ_; ++t){
    float me = ws[OFF_RHO + (size_t)n * 16384 + (size_t)t * 256 + e];
    bool know = false;
    if (t > 0){
      float v0 = fabsf(me - mean0) / sqrtf(var0 + 1e-8f);
      float v1 = fabsf(me - mean1) / sqrtf(var1 + 1e-8f);
      float v2 = fabsf(me - mean2) / sqrtf(var2 + 1e-8f);
      float a = wave_sum(v0), b = wave_sum(v1), c = wave_sum(v2);
      if (lane == 0){ redA[w] = a; redB[w] = b; redC[w] = c; }
      __syncthreads();                               // S1: partials ready
      if (tid == 0){
        float sA = 0.f, sB = 0.f, sC = 0.f;
        #pragma unroll
        for (int i = 0; i < 16; ++i){ sA += redA[i]; sB += redB[i]; sC += redC[i]; }
        size_t base = (size_t)t * 192 + blockIdx.x;
        __hip_atomic_store(&sabsP[base],       sA, __ATOMIC_RELAXED, __HIP_MEMORY_SCOPE_AGENT);
        __hip_atomic_store(&sabsP[base + 64],  sB, __ATOMIC_RELAXED, __HIP_MEMORY_SCOPE_AGENT);
        __hip_atomic_store(&sabsP[base + 128], sC, __ATOMIC_RELAXED, __HIP_MEMORY_SCOPE_AGENT);
        __hip_atomic_fetch_add(bar, 1u, __ATOMIC_ACQ_REL, __HIP_MEMORY_SCOPE_AGENT);
        unsigned tgt = 64u * (unsigned)t;
        while (__hip_atomic_load(bar, __ATOMIC_ACQUIRE, __HIP_MEMORY_SCOPE_AGENT) < tgt)
          __builtin_amdgcn_s_sleep(2);
      }
      __syncthreads();                               // S2: all blocks' partials visible
      // per-wave redundant cross-block reduction (lane l = block l's partial)
      size_t pbase = (size_t)t * 192;
      float p0 = __hip_atomic_load(&sabsP[pbase + lane],       __ATOMIC_RELAXED, __HIP_MEMORY_SCOPE_AGENT);
      float p1 = __hip_atomic_load(&sabsP[pbase + 64 + lane],  __ATOMIC_RELAXED, __HIP_MEMORY_SCOPE_AGENT);
      float p2 = __hip_atomic_load(&sabsP[pbase + 128 + lane], __ATOMIC_RELAXED, __HIP_MEMORY_SCOPE_AGENT);
      float s0 = wave_sum(p0);
      float s1 = wave_sum(p1);
      float s2 = wave_sum(p2);
      know = (s0 < TH) || (s1 < TH) || (s2 < TH);
    }
    float mu = ws[OFF_MU + (size_t)t * 256 + e];
    float eq = c5 * me + (1.0f - c5) * mu;
    float eff = know ? me : eq;

    if (t == 0){
      mean0 = eff; mean1 = eff; mean2 = eff;
      var0 = 0.1f; var1 = 0.1f; var2 = 0.1f;
    } else {
      float um, uv;
      um = 0.3f * mean0 + 0.7f * eff;
      uv = 0.3f * var0 + 0.7f * (eff - mean0) * (eff - um);
      mean0 = um; var0 = fmaxf(uv, 1e-8f);
      um = 0.7f * mean1 + 0.3f * eff;
      uv = 0.7f * var1 + 0.3f * (eff - mean1) * (eff - um);
      mean1 = um; var1 = fmaxf(uv, 1e-8f);
      um = 0.9f * mean2 + 0.1f * eff;
      uv = 0.9f * var2 + 0.1f * (eff - mean2) * (eff - um);
      mean2 = um; var2 = fmaxf(uv, 1e-8f);
    }

    float nv = wave_sum(eff * eff);
    if (lane == 0) redD[w] = nv;
    __syncthreads();                                 // S3: quarter partials
    float nr2 = (redD[4 * q + 0] + redD[4 * q + 1]) + (redD[4 * q + 2] + redD[4 * q + 3]);
    float rn = sqrtf(nr2) + 1e-10f;
    mn16[(size_t)t * 65536 + ne] = __float2bfloat16(eff / rn);
    // no S4: redD(t+1) written after S2(t+1); redA/B/C(t+1) written before S1(t+1),
    // read(t) was before S2(t) -- all hazards separated by S1..S3.
  }
}

// ---------------- K_rho: rho[t] = mn^T mn / NB (fp32 accum from bf16) ----------------
__global__ __launch_bounds__(256) void k_rho(float* __restrict__ ws){
  const int t = blockIdx.x, rb = blockIdx.y, tid = threadIdx.x;
  __shared__ __align__(16) float tile[32][256];
  const unsigned short* mn16 = (const unsigned short*)(ws + OFF_MN16);
  float acc[32];
  #pragma unroll
  for (int i = 0; i < 32; ++i) acc[i] = 0.f;
  for (int c = 0; c < 8; ++c){
    __syncthreads();
    // vectorized: 8192 bf16 per chunk = 1024 uint4; 4 per thread
    #pragma unroll
    for (int v = 0; v < 4; ++v){
      int idx = v * 256 + tid;
      int row = idx >> 5, c16 = idx & 31;
      uint4 u4 = *(const uint4*)(mn16 + (size_t)t * 65536 + (size_t)(c * 32 + row) * 256 + c16 * 8);
      float* dst = &tile[row][c16 * 8];
      unsigned uu[4] = {u4.x, u4.y, u4.z, u4.w};
      #pragma unroll
      for (int j = 0; j < 4; ++j){
        dst[j * 2 + 0] = __uint_as_float(uu[j] << 16);
        dst[j * 2 + 1] = __uint_as_float(uu[j] & 0xffff0000u);
      }
    }
    __syncthreads();
    for (int nl = 0; nl < 32; ++nl){
      float ev = tile[nl][tid];
      #pragma unroll
      for (int q = 0; q < 8; ++q){
        float4 dv = *(const float4*)&tile[nl][rb * 32 + q * 4];
        acc[q * 4 + 0] = fmaf(dv.x, ev, acc[q * 4 + 0]);
        acc[q * 4 + 1] = fmaf(dv.y, ev, acc[q * 4 + 1]);
        acc[q * 4 + 2] = fmaf(dv.z, ev, acc[q * 4 + 2]);
        acc[q * 4 + 3] = fmaf(dv.w, ev, acc[q * 4 + 3]);
      }
    }
  }
  #pragma unroll
  for (int i = 0; i < 32; ++i)
    ws[OFF_RHO + (size_t)t * 65536 + (size_t)(rb * 32 + i) * 256 + tid] = acc[i] * (1.0f / 256.0f);
}

// ---------------- K_trigemm: fused k_tri (blocks 0..63) + k_gemm (blocks 64..16063) ----------------
// EXACT round-9/11 body (measured 1905-1910us fused): tri path writes dT/eT to
// global, NO bisect tail. DO NOT TOUCH (k-loop codegen is fragile).
__global__ __launch_bounds__(512, 2) void k_trigemm(float* __restrict__ ws, float* __restrict__ out){
  __shared__ __align__(16) char smem_raw[51200];
  const int tid = threadIdx.x;

  if (blockIdx.x < 64){
    // ================= TRI PATH =================
    float* ca   = (float*)smem_raw;          // 256
    float* ua   = ca + 256;                  // 256
    float* wa   = ua + 256;                  // 256
    float* ph   = wa + 256;                  // 512
    float* redA = ph + 512;                  // 8
    float* redB = redA + 8;                  // 8
    const int t = blockIdx.x;
    const int c = tid & 255, h = tid >> 8;
    const float* rho = ws + OFF_RHO + (size_t)t * 65536;
    float* dT = ws + OFF_DT + (size_t)t * 256;
    float* eT = ws + OFF_ET + (size_t)t * 256;

    float Mreg[128];
    {
      const float* Mc = rho + (size_t)(h * 128) * 256 + c;
      #pragma unroll
      for (int rr = 0; rr < 128; ++rr)
        Mreg[rr] = Mc[(size_t)rr * 256];
    }
    const int rowbase = h * 128;

    for (int k = 0; k < 254; ++k){
      __syncthreads();                                // S1: prev update done
      if (c == k){
        #pragma unroll
        for (int rr = 0; rr < 128; ++rr) ca[rowbase + rr] = Mreg[rr];
      }
      __syncthreads();                                // S2: ca visible
      float uval = 0.f;
      if (tid < 256){
        float raw = ca[tid];
        uval = (tid > k) ? raw : 0.f;
        ua[tid] = uval;
        if (tid == 0) dT[k] = ca[k];
      }
      float pa = wave_sum(uval * uval);
      if ((tid & 63) == 0) redA[tid >> 6] = pa;
      __syncthreads();                                // S3: ua + redA
      float sigma2 = redA[0] + redA[1] + redA[2] + redA[3]
                   + redA[4] + redA[5] + redA[6] + redA[7];
      float v0 = ca[k + 1];
      if (sigma2 < 1e-30f){                           // uniform branch
        if (tid == 0) eT[k] = v0;
        continue;                                     // H = I
      }
      float sig = sqrtf(sigma2);
      float alpha = (v0 >= 0.f) ? -sig : sig;
      float u0 = v0 - alpha;
      float beta = 2.0f / (sigma2 - v0 * v0 + u0 * u0);
      if (tid == 0) eT[k] = alpha;
      if (tid == k + 1) ua[tid] = u0;
      __syncthreads();                                // S4: u final

      {
        float a0 = 0.f, a1 = 0.f, a2 = 0.f, a3 = 0.f;
        #pragma unroll
        for (int rr = 0; rr < 128; rr += 4){
          float4 u4 = *(const float4*)&ua[rowbase + rr];
          a0 = fmaf(Mreg[rr + 0], u4.x, a0);
          a1 = fmaf(Mreg[rr + 1], u4.y, a1);
          a2 = fmaf(Mreg[rr + 2], u4.z, a2);
          a3 = fmaf(Mreg[rr + 3], u4.w, a3);
        }
        ph[tid] = (a0 + a1) + (a2 + a3);
      }
      __syncthreads();                                // S5: ph
      float p = ph[c] + ph[c + 256];                  // (A u)_c
      float up = (tid < 256) ? ua[tid] * p : 0.f;
      float pb = wave_sum(up);
      if ((tid & 63) == 0) redB[tid >> 6] = pb;
      __syncthreads();                                // S6: redB
      float s = redB[0] + redB[1] + redB[2] + redB[3]
              + redB[4] + redB[5] + redB[6] + redB[7];
      if (tid < 256) wa[tid] = (tid > k) ? (beta * p - 0.5f * beta * beta * s * ua[tid]) : 0.f;
      __syncthreads();                                // S7: wa
      {
        float ucv = ua[c], wcv = wa[c];
        #pragma unroll
        for (int rr = 0; rr < 128; rr += 4){
          float4 u4 = *(const float4*)&ua[rowbase + rr];
          float4 w4 = *(const float4*)&wa[rowbase + rr];
          Mreg[rr + 0] = fmaf(-w4.x, ucv, fmaf(-u4.x, wcv, Mreg[rr + 0]));
          Mreg[rr + 1] = fmaf(-w4.y, ucv, fmaf(-u4.y, wcv, Mreg[rr + 1]));
          Mreg[rr + 2] = fmaf(-w4.z, ucv, fmaf(-u4.z, wcv, Mreg[rr + 2]));
          Mreg[rr + 3] = fmaf(-w4.w, ucv, fmaf(-u4.w, wcv, Mreg[rr + 3]));
        }
      }
    }

    // tail: dT[254], dT[255], eT[254]
    __syncthreads();
    if (c == 254){
      #pragma unroll
      for (int rr = 0; rr < 128; ++rr) ca[rowbase + rr] = Mreg[rr];
    }
    __syncthreads();
    if (tid == 0){ dT[254] = ca[254]; eT[254] = ca[255]; }
    __syncthreads();
    if (c == 255){
      #pragma unroll
      for (int rr = 0; rr < 128; ++rr) ca[rowbase + rr] = Mreg[rr];
    }
    __syncthreads();
    if (tid == 0){ dT[255] = ca[255]; eT[255] = 0.f; }
  } else {
    // ================= GEMM PATH =================
    short* A_lds = (short*)smem_raw;                 // [128 v][8 chunks of 8]
    short* B_lds = A_lds + 8192;                     // [256 n][8 chunks of 8]
    float* pl    = (float*)(B_lds + 16384);          // [8][64]
    const int g = blockIdx.x - 64;
    const int bx = g % 250, t = g / 250;
    const int lane = tid & 63, w = tid >> 6;
    const int wr = w >> 2, wc = w & 3;
    const int vbase = bx * 128;
    const short* E16 = (const short*)(ws + OFF_E16);
    const short* MN  = (const short*)(ws + OFF_MN16) + (size_t)t * 65536;

    f32x4 acc[4][4];
    #pragma unroll
    for (int i = 0; i < 4; ++i)
      #pragma unroll
      for (int j = 0; j < 4; ++j){ f32x4 z = {0.f, 0.f, 0.f, 0.f}; acc[i][j] = z; }

    const int gq = lane >> 4, r16 = lane & 15;
    const int sx = r16 & 7;                          // read-side XOR key
    for (int it = 0; it < 4; ++it){
      const int k0 = it * 64;
      __syncthreads();
      #pragma unroll
      for (int pa = 0; pa < 2; ++pa){
        int ch = pa * 512 + tid;
        int row = ch >> 3, c8 = ch & 7;
        int sc8 = c8 ^ (row & 7);                    // pre-swizzled source chunk
        uint4 v = *(const uint4*)(E16 + (size_t)(vbase + row) * 256 + k0 + sc8 * 8);
        *(uint4*)&A_lds[ch * 8] = v;                 // linear dest (conflict-free)
      }
      #pragma unroll
      for (int pb = 0; pb < 4; ++pb){
        int ch = pb * 512 + tid;
        int row = ch >> 3, c8 = ch & 7;
        int sc8 = c8 ^ (row & 7);
        uint4 v = *(const uint4*)(MN + (size_t)row * 256 + k0 + sc8 * 8);
        *(uint4*)&B_lds[ch * 8] = v;
      }
      __syncthreads();
      #pragma unroll
      for (int kk = 0; kk < 64; kk += 32){
        const int j0 = (kk >> 3) + gq;               // logical chunk index
        bf16x8 af[4], bf[4];
        #pragma unroll
        for (int fm = 0; fm < 4; ++fm)
          af[fm] = *(const bf16x8*)&A_lds[(wr * 64 + fm * 16 + r16) * 64 + (j0 ^ sx) * 8];
        #pragma unroll
        for (int fn = 0; fn < 4; ++fn)
          bf[fn] = *(const bf16x8*)&B_lds[(wc * 64 + fn * 16 + r16) * 64 + (j0 ^ sx) * 8];
        #pragma unroll
        for (int fm = 0; fm < 4; ++fm)
          #pragma unroll
          for (int fn = 0; fn < 4; ++fn)
            acc[fm][fn] = __builtin_amdgcn_mfma_f32_16x16x32_bf16(af[fm], bf[fn], acc[fm][fn], 0, 0, 0);
      }
    }

    // epilogue: square + reduce over n
    float ps[4][4];
    #pragma unroll
    for (int fm = 0; fm < 4; ++fm)
      #pragma unroll
      for (int i = 0; i < 4; ++i){
        float sv = 0.f;
        #pragma unroll
        for (int fn = 0; fn < 4; ++fn){ float v = acc[fm][fn][i]; sv += v * v; }
        sv += __shfl_xor(sv, 1); sv += __shfl_xor(sv, 2);
        sv += __shfl_xor(sv, 4); sv += __shfl_xor(sv, 8);
        ps[fm][i] = sv;
      }
    __syncthreads();
    if (r16 == 0){
      #pragma unroll
      for (int fm = 0; fm < 4; ++fm)
        #pragma unroll
        for (int i = 0; i < 4; ++i)
          pl[w * 64 + fm * 16 + gq * 4 + i] = ps[fm][i];
    }
    __syncthreads();
    if (tid < 128){
      int rr = tid;
      int wrr = rr >> 6, lr = rr & 63;
      float sum = pl[(wrr * 4 + 0) * 64 + lr] + pl[(wrr * 4 + 1) * 64 + lr]
                + pl[(wrr * 4 + 2) * 64 + lr] + pl[(wrr * 4 + 3) * 64 + lr];
      out[(size_t)t * VOCAB_ + vbase + rr] = sum * (1.0f / 256.0f);
    }
  }
}

// ---------------- K_bisect: Sturm bisection, one eigenvalue per thread ----------------
__global__ __launch_bounds__(256) void k_bisect(const float* __restrict__ ws, float* __restrict__ out){
  __shared__ float d_s[256];
  __shared__ float e2_s[256];
  __shared__ float ea_s[256];
  __shared__ float red[4];
  const int t = blockIdx.x, tid = threadIdx.x;
  d_s[tid] = ws[OFF_DT + (size_t)t * 256 + tid];
  float evv = (tid < 255) ? ws[OFF_ET + (size_t)t * 256 + tid] : 0.f;
  e2_s[tid] = evv * evv;
  ea_s[tid] = fabsf(evv);
  __syncthreads();
  float rad = ea_s[tid] + ((tid > 0) ? ea_s[tid - 1] : 0.f);
  float glo = block_min(d_s[tid] - rad, red);
  float ghi = block_max(d_s[tid] + rad, red);

  float l = glo, h = ghi;
  for (int it = 0; it < 40; ++it){
    float mid = 0.5f * (l + h);
    float q = d_s[0] - mid;
    int cnt = (q < 0.f) ? 1 : 0;
    #pragma unroll 8
    for (int i = 1; i < 256; ++i){
      float qr = __builtin_amdgcn_rcpf(q);
      q = (d_s[i] - mid) - e2_s[i - 1] * qr;
      q = (fabsf(q) < 1e-25f) ? -1e-25f : q;
      cnt += (q < 0.f) ? 1 : 0;
    }
    if (cnt <= tid) l = mid; else h = mid;
  }
  float lam = fmaxf(0.5f * (l + h), 1e-12f);
  float ssum = block_sum(lam, red);
  out[(size_t)SEQ_ * VOCAB_ + (size_t)t * 256 + tid] = lam / ssum;
}

// ---------------- host ----------------
extern "C" void kernel_launch(void* const* d_in, const int* in_sizes, int n_in,
                              void* d_out, int out_size, void* d_ws, size_t ws_size,
                              hipStream_t stream){
  const int*   tokens = (const int*)d_in[0];
  const float* E      = (const float*)d_in[1];
  const float* W      = (const float*)d_in[2];
  const float* mdbp   = (const float*)d_in[3];
  const float* nsp    = (const float*)d_in[4];
  float* out = (float*)d_out;
  float* ws  = (float*)d_ws;
  if (ws_size < WS_FLOATS * sizeof(float)) return;   // insufficient scratch -> clean fail

  k0_init<<<dim3(32000), dim3(256), 0, stream>>>(E, W, ws);
  k_xm<<<dim3(1), dim3(1024), 0, stream>>>(tokens, E, mdbp, nsp, ws);
  k_measall<<<dim3(256), dim3(256), 0, stream>>>(W, ws);
  {
    void* args[1];
    args[0] = (void*)&ws;
    hipLaunchCooperativeKernel((const void*)k_stats, dim3(64), dim3(1024), args, 0, stream);
  }
  k_rho<<<dim3(64, 8), dim3(256), 0, stream>>>(ws);
  k_trigemm<<<dim3(64 + 250 * 64), dim3(512), 0, stream>>>(ws, out);
  k_bisect<<<dim3(64), dim3(256), 0, stream>>>(ws, out);
}